// Round 2
// baseline (1400.844 us; speedup 1.0000x reference)
//
#include <hip/hip_runtime.h>
#include <math.h>

#define NUM_NODES 150000
#define DIM 64
#define N_EDGES 3200000
#define BATCH 1024
#define N_NEGS 40
#define REG_COEF 1e-4f
#define SCAN_B 1024
#define NB ((NUM_NODES + SCAN_B - 1) / SCAN_B)   // 147
#define C_BITS 7
#define BUCKET_C 128
#define NBUCKETS ((NUM_NODES + BUCKET_C - 1) / BUCKET_C)  // 1172

// ---------------- degree count ----------------
__global__ void count_deg_kernel(const int* __restrict__ col, int* __restrict__ deg) {
    int e = blockIdx.x * blockDim.x + threadIdx.x;
    if (e < N_EDGES) atomicAdd(&deg[col[e]], 1);
}

// ---------------- scan (3 kernels) -> off[NUM_NODES+1], off[0]=0 ----------------
__global__ void scan_partial_kernel(const int* __restrict__ deg, int* __restrict__ partial) {
    int t = threadIdx.x;
    int g = blockIdx.x * SCAN_B + t;
    int v = (g < NUM_NODES) ? deg[g] : 0;
    for (int m = 1; m < 64; m <<= 1) v += __shfl_xor(v, m);
    __shared__ int ws[16];
    if ((t & 63) == 0) ws[t >> 6] = v;
    __syncthreads();
    if (t < 16) {
        int s = ws[t];
        for (int m = 1; m < 16; m <<= 1) s += __shfl_xor(s, m);
        if (t == 0) partial[blockIdx.x] = s;
    }
}

__global__ void scan_base_kernel(int* __restrict__ partial) {
    // single wave, 3 chunks of 64 covering NB=147
    int l = threadIdx.x;
    int carry = 0;
    for (int c = 0; c < 3; c++) {
        int idx = c * 64 + l;
        int v = (idx < NB) ? partial[idx] : 0;
        int inc = v;
        for (int m = 1; m < 64; m <<= 1) {
            int t = __shfl_up(inc, m);
            if (l >= m) inc += t;
        }
        int excl = inc - v + carry;
        if (idx < NB) partial[idx] = excl;
        carry += __shfl(inc, 63);
    }
}

__global__ void scan_apply_kernel(const int* __restrict__ deg, const int* __restrict__ partial,
                                  int* __restrict__ off) {
    __shared__ int lds[SCAN_B];
    int t = threadIdx.x;
    int g = blockIdx.x * SCAN_B + t;
    int v = (g < NUM_NODES) ? deg[g] : 0;
    int val = v;
    lds[t] = val;
    __syncthreads();
    for (int o = 1; o < SCAN_B; o <<= 1) {
        int add = (t >= o) ? lds[t - o] : 0;
        __syncthreads();
        val += add;
        lds[t] = val;
        __syncthreads();
    }
    if (g < NUM_NODES) off[g + 1] = partial[blockIdx.x] + val;  // inclusive -> off[g+1]
}

// ---------------- dinv ----------------
__global__ void dinv_kernel(const int* __restrict__ deg, float* __restrict__ dinv) {
    int g = blockIdx.x * blockDim.x + threadIdx.x;
    if (g < NUM_NODES) {
        int d = deg[g];
        dinv[g] = (d > 0) ? rsqrtf((float)d) : 0.f;
    }
}

// ---------------- bucket cursor init: bcur[b] = off[b*128] ----------------
__global__ void init_bcur_kernel(const int* __restrict__ off, int* __restrict__ bcur) {
    int b = blockIdx.x * blockDim.x + threadIdx.x;
    if (b < NBUCKETS) bcur[b] = off[b << C_BITS];
}

// ---------------- pass B: scatter edges into bucket-ordered staging ----------------
// staging word packs (col & 127) << 18 | row   (row < 2^18, local col < 2^7)
__global__ void scatter_kernel(const int* __restrict__ row, const int* __restrict__ col,
                               int* __restrict__ bcur, unsigned* __restrict__ staging) {
    int e = blockIdx.x * blockDim.x + threadIdx.x;
    if (e < N_EDGES) {
        int c = col[e];
        int b = c >> C_BITS;
        int pos = atomicAdd(&bcur[b], 1);
        staging[pos] = ((unsigned)(c & (BUCKET_C - 1)) << 18) | (unsigned)row[e];
    }
}

// ---------------- pass C: per-bucket local fill with LDS cursors ----------------
__global__ __launch_bounds__(256) void fill2_kernel(const int* __restrict__ off,
                                                    const unsigned* __restrict__ staging,
                                                    int* __restrict__ csr_row) {
    __shared__ int cur[BUCKET_C];
    int b = blockIdx.x;
    int node0 = b << C_BITS;
    int nn = NUM_NODES - node0; if (nn > BUCKET_C) nn = BUCKET_C;
    int t = threadIdx.x;
    if (t < nn) cur[t] = off[node0 + t];
    __syncthreads();
    int bstart = off[node0];
    int bend = off[(node0 + BUCKET_C < NUM_NODES) ? node0 + BUCKET_C : NUM_NODES];
    for (int i = bstart + t; i < bend; i += 256) {
        unsigned s = staging[i];
        int local = (int)(s >> 18);
        int r = (int)(s & 0x3FFFFu);
        int pos = atomicAdd(&cur[local], 1);
        csr_row[pos] = r;
    }
}

// ---------------- conv: y[c] = dinv[c] * sum_{in-edges} dinv[row] * x[row] ----------------
__global__ __launch_bounds__(256) void conv_kernel(const int* __restrict__ off,
                                                   const int* __restrict__ csr_row,
                                                   const float* __restrict__ dinv,
                                                   const float* __restrict__ x,
                                                   float* __restrict__ y) {
    int wid = (blockIdx.x * blockDim.x + threadIdx.x) >> 6;
    int lane = threadIdx.x & 63;
    if (wid >= NUM_NODES) return;
    int start = off[wid];
    int end = off[wid + 1];
    float acc = 0.f;
    int i = start;
    for (; i + 1 < end; i += 2) {
        int r0 = csr_row[i];
        int r1 = csr_row[i + 1];
        float d0 = dinv[r0];
        float d1 = dinv[r1];
        float v0 = x[(size_t)r0 * DIM + lane];
        float v1 = x[(size_t)r1 * DIM + lane];
        acc += d0 * v0 + d1 * v1;
    }
    if (i < end) {
        int r0 = csr_row[i];
        acc += dinv[r0] * x[(size_t)r0 * DIM + lane];
    }
    y[(size_t)wid * DIM + lane] = acc * dinv[wid];
}

// ---------------- fused node-wise: z_p avg, MLP, attention, Z ----------------
__global__ __launch_bounds__(256) void fuse_kernel(
    const float* __restrict__ E, const float* __restrict__ E2,
    const float* __restrict__ W0, const float* __restrict__ b0,
    const float* __restrict__ W1, const float* __restrict__ b1,
    const float* __restrict__ AW, const float* __restrict__ ab,
    const float* __restrict__ qW,
    const float* x1, const float* x2, float* Z) {
    __shared__ __align__(16) float W0q[4096];
    __shared__ __align__(16) float W1q[4096];
    __shared__ __align__(16) float AWq[4096];
    __shared__ float bb0[64], bb1[64], bab[64], qb[64];
    __shared__ __align__(16) float xbuf[4][64];
    __shared__ __align__(16) float hbuf[4][64];
    __shared__ __align__(16) float zpb[4][64];
    __shared__ __align__(16) float znb[4][64];

    int t = threadIdx.x;
    for (int idx = t; idx < 4096; idx += 256) {
        int j = idx >> 6, k = idx & 63;
        int dst = (k >> 2) * 256 + j * 4 + (k & 3);
        W0q[dst] = W0[idx];
        W1q[dst] = W1[idx];
        AWq[dst] = AW[idx];
    }
    if (t < 64) { bb0[t] = b0[t]; bb1[t] = b1[t]; bab[t] = ab[t]; qb[t] = qW[t]; }
    __syncthreads();

    const int lane = t & 63, w = t >> 6;
    for (int nd = blockIdx.x * 4 + w; nd < NUM_NODES; nd += gridDim.x * 4) {
        size_t base = (size_t)nd * DIM + lane;
        float zp = (E[base] + x1[base] + x2[base]) * (1.f / 3.f);
        float e2v = E2[base];
        zpb[w][lane] = zp;
        xbuf[w][lane] = e2v;
        __syncthreads();

        float s = bb0[lane];
#pragma unroll
        for (int k4 = 0; k4 < 16; k4++) {
            float4 wq = *(const float4*)&W0q[k4 * 256 + lane * 4];
            float4 xq = *(const float4*)&xbuf[w][k4 * 4];
            s += wq.x * xq.x + wq.y * xq.y + wq.z * xq.z + wq.w * xq.w;
        }
        float h = fmaxf(s, 0.f);
        hbuf[w][lane] = h;
        __syncthreads();

        s = bb1[lane];
#pragma unroll
        for (int k4 = 0; k4 < 16; k4++) {
            float4 wq = *(const float4*)&W1q[k4 * 256 + lane * 4];
            float4 xq = *(const float4*)&hbuf[w][k4 * 4];
            s += wq.x * xq.x + wq.y * xq.y + wq.z * xq.z + wq.w * xq.w;
        }
        float zn = fmaxf(s, 0.f);
        znb[w][lane] = zn;
        __syncthreads();

        float sp = bab[lane], sn = bab[lane];
#pragma unroll
        for (int k4 = 0; k4 < 16; k4++) {
            float4 wq = *(const float4*)&AWq[k4 * 256 + lane * 4];
            float4 zq = *(const float4*)&zpb[w][k4 * 4];
            float4 nq = *(const float4*)&znb[w][k4 * 4];
            sp += wq.x * zq.x + wq.y * zq.y + wq.z * zq.z + wq.w * zq.w;
            sn += wq.x * nq.x + wq.y * nq.y + wq.z * nq.z + wq.w * nq.w;
        }
        float tp = tanhf(sp) * qb[lane];
        float tn = tanhf(sn) * qb[lane];
        for (int m = 1; m < 64; m <<= 1) {
            tp += __shfl_xor(tp, m);
            tn += __shfl_xor(tn, m);
        }
        float mx = fmaxf(tp, tn);
        float ep = expf(tp - mx), en = expf(tn - mx);
        float inv = 1.f / (ep + en);
        Z[base] = (ep * zp + en * zn) * inv;
        __syncthreads();
    }
}

// ---------------- loss ----------------
__global__ __launch_bounds__(256) void loss_kernel(const float* __restrict__ Z,
                                                   const float* __restrict__ wv,
                                                   const int* __restrict__ u,
                                                   const int* __restrict__ v,
                                                   const int* __restrict__ n,
                                                   float* __restrict__ out) {
    int wid = (blockIdx.x * blockDim.x + threadIdx.x) >> 6;
    int lane = threadIdx.x & 63;
    if (wid >= BATCH) return;
    float uu = Z[(size_t)u[wid] * DIM + lane];
    float vv = Z[(size_t)v[wid] * DIM + lane];
    float pos = uu * vv;
    for (int m = 1; m < 64; m <<= 1) pos += __shfl_xor(pos, m);
    float reg = uu * uu + vv * vv;
    float wval = wv[wid];
    float sgn = (wval > 0.f ? 1.f : 0.f) - (wval < 0.f ? 1.f : 0.f);
    float coef = -0.5f * sgn + 1.5f;
    float cp = coef * pos;
    float sb = 0.f;
    for (int k = 0; k < N_NEGS; k++) {
        int nid = n[wid * N_NEGS + k];
        float nn = Z[(size_t)nid * DIM + lane];
        float d = uu * nn;
        for (int m = 1; m < 64; m <<= 1) d += __shfl_xor(d, m);
        reg += nn * nn;
        float x = cp - d;
        float ls = (x >= 0.f) ? -log1pf(expf(-x)) : (x - log1pf(expf(x)));
        sb += ls;
    }
    for (int m = 1; m < 64; m <<= 1) reg += __shfl_xor(reg, m);
    if (lane == 0) atomicAdd(out, -sb + REG_COEF * reg);
}

extern "C" void kernel_launch(void* const* d_in, const int* in_sizes, int n_in,
                              void* d_out, int out_size, void* d_ws, size_t ws_size,
                              hipStream_t stream) {
    const float* E  = (const float*)d_in[0];
    const float* E2 = (const float*)d_in[1];
    const float* W0 = (const float*)d_in[2];
    const float* b0 = (const float*)d_in[3];
    const float* W1 = (const float*)d_in[4];
    const float* b1 = (const float*)d_in[5];
    const float* AW = (const float*)d_in[6];
    const float* ab = (const float*)d_in[7];
    const float* qW = (const float*)d_in[8];
    const float* wv = (const float*)d_in[9];
    const int* ei   = (const int*)d_in[10];
    const int* uu   = (const int*)d_in[11];
    const int* vv   = (const int*)d_in[12];
    const int* nn   = (const int*)d_in[13];
    const int* row = ei;
    const int* col = ei + N_EDGES;

    char* ws = (char*)d_ws;
    size_t p = 0;
    auto align_up = [](size_t x) { return (x + 255) & ~(size_t)255; };
    int* off      = (int*)(ws + p); p = align_up(p + (size_t)(NUM_NODES + 1) * 4);
    int* deg      = (int*)(ws + p); p = align_up(p + (size_t)NUM_NODES * 4);
    float* dinv   = (float*)(ws + p); p = align_up(p + (size_t)NUM_NODES * 4);
    int* partial  = (int*)(ws + p); p = align_up(p + (size_t)NB * 4);
    int* bcur     = (int*)(ws + p); p = align_up(p + (size_t)NBUCKETS * 4);
    int* csr_row  = (int*)(ws + p); p = align_up(p + (size_t)N_EDGES * 4);
    float* x1     = (float*)(ws + p); p = align_up(p + (size_t)NUM_NODES * DIM * 4);
    float* x2     = (float*)(ws + p); p = align_up(p + (size_t)NUM_NODES * DIM * 4);
    float* Z = x1;                 // alias: fuse reads x1[i] then writes Z[i] same thread
    unsigned* staging = (unsigned*)x2;  // alias: staging consumed before conv writes x2

    hipMemsetAsync(deg, 0, (size_t)NUM_NODES * 4, stream);
    hipMemsetAsync(off, 0, 4, stream);
    hipMemsetAsync(d_out, 0, sizeof(float), stream);

    count_deg_kernel<<<(N_EDGES + 255) / 256, 256, 0, stream>>>(col, deg);
    scan_partial_kernel<<<NB, SCAN_B, 0, stream>>>(deg, partial);
    scan_base_kernel<<<1, 64, 0, stream>>>(partial);
    scan_apply_kernel<<<NB, SCAN_B, 0, stream>>>(deg, partial, off);
    dinv_kernel<<<(NUM_NODES + 255) / 256, 256, 0, stream>>>(deg, dinv);

    init_bcur_kernel<<<(NBUCKETS + 255) / 256, 256, 0, stream>>>(off, bcur);
    scatter_kernel<<<(N_EDGES + 255) / 256, 256, 0, stream>>>(row, col, bcur, staging);
    fill2_kernel<<<NBUCKETS, 256, 0, stream>>>(off, staging, csr_row);

    conv_kernel<<<NUM_NODES / 4, 256, 0, stream>>>(off, csr_row, dinv, E, x1);
    conv_kernel<<<NUM_NODES / 4, 256, 0, stream>>>(off, csr_row, dinv, x1, x2);

    fuse_kernel<<<2048, 256, 0, stream>>>(E, E2, W0, b0, W1, b1, AW, ab, qW, x1, x2, Z);

    loss_kernel<<<BATCH * 64 / 256, 256, 0, stream>>>(Z, wv, uu, vv, nn, (float*)d_out);
}

// Round 3
// 735.331 us; speedup vs baseline: 1.9051x; 1.9051x over previous
//
#include <hip/hip_runtime.h>
#include <math.h>

#define NUM_NODES 150000
#define DIM 64
#define N_EDGES 3200000
#define BATCH 1024
#define N_NEGS 40
#define REG_COEF 1e-4f

#define BK_BITS 9
#define BK_NODES 512
#define NBK ((NUM_NODES + BK_NODES - 1) >> BK_BITS)      // 293
#define TILE 8192
#define NT ((N_EDGES + TILE - 1) / TILE)                 // 391
#define HSIZE (NBK * NT)                                 // 114563
#define SCAN_B 1024
#define NB2 ((HSIZE + SCAN_B - 1) / SCAN_B)              // 112

// ---------------- pass 1: per-tile bucket histogram ----------------
__global__ __launch_bounds__(256) void histo_kernel(const int* __restrict__ col,
                                                    int* __restrict__ hist) {
    __shared__ int h[NBK];
    int t = threadIdx.x;
    for (int i = t; i < NBK; i += 256) h[i] = 0;
    __syncthreads();
    int e0 = blockIdx.x * TILE;
    int e1 = e0 + TILE; if (e1 > N_EDGES) e1 = N_EDGES;
    for (int i = e0 + t; i < e1; i += 256) atomicAdd(&h[col[i] >> BK_BITS], 1);
    __syncthreads();
    for (int i = t; i < NBK; i += 256) hist[i * NT + blockIdx.x] = h[i];
}

// ---------------- scan (3 kernels) over hist[HSIZE] -> exclusive in-place ----------------
__global__ void scan_partial_kernel(const int* __restrict__ src, int* __restrict__ partial, int n) {
    int t = threadIdx.x;
    int g = blockIdx.x * SCAN_B + t;
    int v = (g < n) ? src[g] : 0;
    for (int m = 1; m < 64; m <<= 1) v += __shfl_xor(v, m);
    __shared__ int ws[16];
    if ((t & 63) == 0) ws[t >> 6] = v;
    __syncthreads();
    if (t < 16) {
        int s = ws[t];
        for (int m = 1; m < 16; m <<= 1) s += __shfl_xor(s, m);
        if (t == 0) partial[blockIdx.x] = s;
    }
}

__global__ void scan_base_kernel(int* __restrict__ partial, int nb, int chunks) {
    int l = threadIdx.x;
    int carry = 0;
    for (int c = 0; c < chunks; c++) {
        int idx = c * 64 + l;
        int v = (idx < nb) ? partial[idx] : 0;
        int inc = v;
        for (int m = 1; m < 64; m <<= 1) {
            int t = __shfl_up(inc, m);
            if (l >= m) inc += t;
        }
        int excl = inc - v + carry;
        if (idx < nb) partial[idx] = excl;
        carry += __shfl(inc, 63);
    }
}

__global__ void scan_apply_kernel(int* __restrict__ data, const int* __restrict__ partial, int n) {
    __shared__ int lds[SCAN_B];
    int t = threadIdx.x;
    int g = blockIdx.x * SCAN_B + t;
    int v = (g < n) ? data[g] : 0;
    int val = v;
    lds[t] = val;
    __syncthreads();
    for (int o = 1; o < SCAN_B; o <<= 1) {
        int add = (t >= o) ? lds[t - o] : 0;
        __syncthreads();
        val += add;
        lds[t] = val;
        __syncthreads();
    }
    if (g < n) data[g] = partial[blockIdx.x] + val - v;  // exclusive
}

// ---------------- pass 2: rank-based partition into bucket-grouped staging ----------------
// staging word: (col & 511) << 18 | row   (row < 2^18)
__global__ __launch_bounds__(256) void partition_kernel(const int* __restrict__ row,
                                                        const int* __restrict__ col,
                                                        const int* __restrict__ hist,
                                                        unsigned* __restrict__ staging) {
    __shared__ int base[NBK];
    __shared__ int cnt[NBK];
    int t = threadIdx.x;
    for (int i = t; i < NBK; i += 256) { base[i] = hist[i * NT + blockIdx.x]; cnt[i] = 0; }
    __syncthreads();
    int e0 = blockIdx.x * TILE;
    int e1 = e0 + TILE; if (e1 > N_EDGES) e1 = N_EDGES;
    for (int i = e0 + t; i < e1; i += 256) {
        int c = col[i];
        int b = c >> BK_BITS;
        int r = atomicAdd(&cnt[b], 1);
        staging[base[b] + r] = ((unsigned)(c & (BK_NODES - 1)) << 18) | (unsigned)row[i];
    }
}

// ---------------- pass 3: per-bucket node offsets + dinv + final CSR ----------------
__global__ __launch_bounds__(512) void fill3_kernel(const int* __restrict__ hist,
                                                    const unsigned* __restrict__ staging,
                                                    int* __restrict__ off,
                                                    float* __restrict__ dinv,
                                                    int* __restrict__ csr_row) {
    __shared__ int cnt[BK_NODES];
    __shared__ int lds[BK_NODES];
    int b = blockIdx.x;
    int t = threadIdx.x;
    int node0 = b << BK_BITS;
    int bstart = hist[b * NT];
    int bend = (b + 1 < NBK) ? hist[(b + 1) * NT] : N_EDGES;
    cnt[t] = 0;
    __syncthreads();
    for (int i = bstart + t; i < bend; i += 512) atomicAdd(&cnt[staging[i] >> 18], 1);
    __syncthreads();
    int v = cnt[t];
    int val = v;
    lds[t] = val;
    __syncthreads();
    for (int o = 1; o < BK_NODES; o <<= 1) {
        int add = (t >= o) ? lds[t - o] : 0;
        __syncthreads();
        val += add;
        lds[t] = val;
        __syncthreads();
    }
    int cursor = bstart + val - v;   // exclusive
    int node = node0 + t;
    if (node < NUM_NODES) {
        off[node] = cursor;
        dinv[node] = (v > 0) ? rsqrtf((float)v) : 0.f;
    }
    cnt[t] = cursor;
    __syncthreads();
    for (int i = bstart + t; i < bend; i += 512) {
        unsigned s = staging[i];
        int pos = atomicAdd(&cnt[s >> 18], 1);
        csr_row[pos] = (int)(s & 0x3FFFFu);
    }
    if (b == 0 && t == 0) off[NUM_NODES] = N_EDGES;
}

// ---------------- conv: y[c] = dinv[c] * sum_{in-edges} dinv[row] * x[row] ----------------
__global__ __launch_bounds__(256) void conv_kernel(const int* __restrict__ off,
                                                   const int* __restrict__ csr_row,
                                                   const float* __restrict__ dinv,
                                                   const float* __restrict__ x,
                                                   float* __restrict__ y) {
    int wid = (blockIdx.x * blockDim.x + threadIdx.x) >> 6;
    int lane = threadIdx.x & 63;
    if (wid >= NUM_NODES) return;
    int start = off[wid];
    int end = off[wid + 1];
    float acc = 0.f;
    int i = start;
    for (; i + 1 < end; i += 2) {
        int r0 = csr_row[i];
        int r1 = csr_row[i + 1];
        float d0 = dinv[r0];
        float d1 = dinv[r1];
        float v0 = x[(size_t)r0 * DIM + lane];
        float v1 = x[(size_t)r1 * DIM + lane];
        acc += d0 * v0 + d1 * v1;
    }
    if (i < end) {
        int r0 = csr_row[i];
        acc += dinv[r0] * x[(size_t)r0 * DIM + lane];
    }
    y[(size_t)wid * DIM + lane] = acc * dinv[wid];
}

// ---------------- fused node-wise: z_p avg, MLP, attention, Z ----------------
__global__ __launch_bounds__(256) void fuse_kernel(
    const float* __restrict__ E, const float* __restrict__ E2,
    const float* __restrict__ W0, const float* __restrict__ b0,
    const float* __restrict__ W1, const float* __restrict__ b1,
    const float* __restrict__ AW, const float* __restrict__ ab,
    const float* __restrict__ qW,
    const float* x1, const float* x2, float* Z) {
    __shared__ __align__(16) float W0q[4096];
    __shared__ __align__(16) float W1q[4096];
    __shared__ __align__(16) float AWq[4096];
    __shared__ float bb0[64], bb1[64], bab[64], qb[64];
    __shared__ __align__(16) float xbuf[4][64];
    __shared__ __align__(16) float hbuf[4][64];
    __shared__ __align__(16) float zpb[4][64];
    __shared__ __align__(16) float znb[4][64];

    int t = threadIdx.x;
    for (int idx = t; idx < 4096; idx += 256) {
        int j = idx >> 6, k = idx & 63;
        int dst = (k >> 2) * 256 + j * 4 + (k & 3);
        W0q[dst] = W0[idx];
        W1q[dst] = W1[idx];
        AWq[dst] = AW[idx];
    }
    if (t < 64) { bb0[t] = b0[t]; bb1[t] = b1[t]; bab[t] = ab[t]; qb[t] = qW[t]; }
    __syncthreads();

    const int lane = t & 63, w = t >> 6;
    for (int nd = blockIdx.x * 4 + w; nd < NUM_NODES; nd += gridDim.x * 4) {
        size_t base = (size_t)nd * DIM + lane;
        float zp = (E[base] + x1[base] + x2[base]) * (1.f / 3.f);
        float e2v = E2[base];
        zpb[w][lane] = zp;
        xbuf[w][lane] = e2v;
        __syncthreads();

        float s = bb0[lane];
#pragma unroll
        for (int k4 = 0; k4 < 16; k4++) {
            float4 wq = *(const float4*)&W0q[k4 * 256 + lane * 4];
            float4 xq = *(const float4*)&xbuf[w][k4 * 4];
            s += wq.x * xq.x + wq.y * xq.y + wq.z * xq.z + wq.w * xq.w;
        }
        float h = fmaxf(s, 0.f);
        hbuf[w][lane] = h;
        __syncthreads();

        s = bb1[lane];
#pragma unroll
        for (int k4 = 0; k4 < 16; k4++) {
            float4 wq = *(const float4*)&W1q[k4 * 256 + lane * 4];
            float4 xq = *(const float4*)&hbuf[w][k4 * 4];
            s += wq.x * xq.x + wq.y * xq.y + wq.z * xq.z + wq.w * xq.w;
        }
        float zn = fmaxf(s, 0.f);
        znb[w][lane] = zn;
        __syncthreads();

        float sp = bab[lane], sn = bab[lane];
#pragma unroll
        for (int k4 = 0; k4 < 16; k4++) {
            float4 wq = *(const float4*)&AWq[k4 * 256 + lane * 4];
            float4 zq = *(const float4*)&zpb[w][k4 * 4];
            float4 nq = *(const float4*)&znb[w][k4 * 4];
            sp += wq.x * zq.x + wq.y * zq.y + wq.z * zq.z + wq.w * zq.w;
            sn += wq.x * nq.x + wq.y * nq.y + wq.z * nq.z + wq.w * nq.w;
        }
        float tp = tanhf(sp) * qb[lane];
        float tn = tanhf(sn) * qb[lane];
        for (int m = 1; m < 64; m <<= 1) {
            tp += __shfl_xor(tp, m);
            tn += __shfl_xor(tn, m);
        }
        float mx = fmaxf(tp, tn);
        float ep = expf(tp - mx), en = expf(tn - mx);
        float inv = 1.f / (ep + en);
        Z[base] = (ep * zp + en * zn) * inv;
        __syncthreads();
    }
}

// ---------------- loss ----------------
__global__ __launch_bounds__(256) void loss_kernel(const float* __restrict__ Z,
                                                   const float* __restrict__ wv,
                                                   const int* __restrict__ u,
                                                   const int* __restrict__ v,
                                                   const int* __restrict__ n,
                                                   float* __restrict__ out) {
    int wid = (blockIdx.x * blockDim.x + threadIdx.x) >> 6;
    int lane = threadIdx.x & 63;
    if (wid >= BATCH) return;
    float uu = Z[(size_t)u[wid] * DIM + lane];
    float vv = Z[(size_t)v[wid] * DIM + lane];
    float pos = uu * vv;
    for (int m = 1; m < 64; m <<= 1) pos += __shfl_xor(pos, m);
    float reg = uu * uu + vv * vv;
    float wval = wv[wid];
    float sgn = (wval > 0.f ? 1.f : 0.f) - (wval < 0.f ? 1.f : 0.f);
    float coef = -0.5f * sgn + 1.5f;
    float cp = coef * pos;
    float sb = 0.f;
    for (int k = 0; k < N_NEGS; k++) {
        int nid = n[wid * N_NEGS + k];
        float nn = Z[(size_t)nid * DIM + lane];
        float d = uu * nn;
        for (int m = 1; m < 64; m <<= 1) d += __shfl_xor(d, m);
        reg += nn * nn;
        float x = cp - d;
        float ls = (x >= 0.f) ? -log1pf(expf(-x)) : (x - log1pf(expf(x)));
        sb += ls;
    }
    for (int m = 1; m < 64; m <<= 1) reg += __shfl_xor(reg, m);
    if (lane == 0) atomicAdd(out, -sb + REG_COEF * reg);
}

extern "C" void kernel_launch(void* const* d_in, const int* in_sizes, int n_in,
                              void* d_out, int out_size, void* d_ws, size_t ws_size,
                              hipStream_t stream) {
    const float* E  = (const float*)d_in[0];
    const float* E2 = (const float*)d_in[1];
    const float* W0 = (const float*)d_in[2];
    const float* b0 = (const float*)d_in[3];
    const float* W1 = (const float*)d_in[4];
    const float* b1 = (const float*)d_in[5];
    const float* AW = (const float*)d_in[6];
    const float* ab = (const float*)d_in[7];
    const float* qW = (const float*)d_in[8];
    const float* wv = (const float*)d_in[9];
    const int* ei   = (const int*)d_in[10];
    const int* uu   = (const int*)d_in[11];
    const int* vv   = (const int*)d_in[12];
    const int* nn   = (const int*)d_in[13];
    const int* row = ei;
    const int* col = ei + N_EDGES;

    char* ws = (char*)d_ws;
    size_t p = 0;
    auto align_up = [](size_t x) { return (x + 255) & ~(size_t)255; };
    int* off      = (int*)(ws + p); p = align_up(p + (size_t)(NUM_NODES + 1) * 4);
    float* dinv   = (float*)(ws + p); p = align_up(p + (size_t)NUM_NODES * 4);
    int* hist     = (int*)(ws + p); p = align_up(p + (size_t)HSIZE * 4);
    int* partial  = (int*)(ws + p); p = align_up(p + (size_t)NB2 * 4);
    int* csr_row  = (int*)(ws + p); p = align_up(p + (size_t)N_EDGES * 4);
    float* x1     = (float*)(ws + p); p = align_up(p + (size_t)NUM_NODES * DIM * 4);
    float* x2     = (float*)(ws + p); p = align_up(p + (size_t)NUM_NODES * DIM * 4);
    float* Z = x1;                      // alias: fuse reads x1[i] then writes Z[i] same thread
    unsigned* staging = (unsigned*)x2;  // alias: staging consumed before conv writes x2

    hipMemsetAsync(d_out, 0, sizeof(float), stream);

    histo_kernel<<<NT, 256, 0, stream>>>(col, hist);
    scan_partial_kernel<<<NB2, SCAN_B, 0, stream>>>(hist, partial, HSIZE);
    scan_base_kernel<<<1, 64, 0, stream>>>(partial, NB2, 2);
    scan_apply_kernel<<<NB2, SCAN_B, 0, stream>>>(hist, partial, HSIZE);
    partition_kernel<<<NT, 256, 0, stream>>>(row, col, hist, staging);
    fill3_kernel<<<NBK, 512, 0, stream>>>(hist, staging, off, dinv, csr_row);

    conv_kernel<<<NUM_NODES / 4, 256, 0, stream>>>(off, csr_row, dinv, E, x1);
    conv_kernel<<<NUM_NODES / 4, 256, 0, stream>>>(off, csr_row, dinv, x1, x2);

    fuse_kernel<<<2048, 256, 0, stream>>>(E, E2, W0, b0, W1, b1, AW, ab, qW, x1, x2, Z);

    loss_kernel<<<BATCH * 64 / 256, 256, 0, stream>>>(Z, wv, uu, vv, nn, (float*)d_out);
}

// Round 4
// 404.192 us; speedup vs baseline: 3.4658x; 1.8193x over previous
//
#include <hip/hip_runtime.h>
#include <math.h>

#define NUM_NODES 150000
#define DIM 64
#define N_EDGES 3200000
#define BATCH 1024
#define N_NEGS 40
#define REG_COEF 1e-4f

#define BK_BITS 9
#define BK_NODES 512
#define NBK ((NUM_NODES + BK_NODES - 1) >> BK_BITS)      // 293
#define TILE 8192
#define NT ((N_EDGES + TILE - 1) / TILE)                 // 391
#define HSIZE (NBK * NT)                                 // 114563
#define SCAN_B 1024
#define NB2 ((HSIZE + SCAN_B - 1) / SCAN_B)              // 112
#define NLIST (BATCH * (N_NEGS + 2))                     // 43008

// ---------------- pass 1: per-tile bucket histogram ----------------
__global__ __launch_bounds__(256) void histo_kernel(const int* __restrict__ col,
                                                    int* __restrict__ hist) {
    __shared__ int h[NBK];
    int t = threadIdx.x;
    for (int i = t; i < NBK; i += 256) h[i] = 0;
    __syncthreads();
    int e0 = blockIdx.x * TILE;
    int e1 = e0 + TILE; if (e1 > N_EDGES) e1 = N_EDGES;
    for (int i = e0 + t; i < e1; i += 256) atomicAdd(&h[col[i] >> BK_BITS], 1);
    __syncthreads();
    for (int i = t; i < NBK; i += 256) hist[i * NT + blockIdx.x] = h[i];
}

// ---------------- scan (3 kernels) over hist[HSIZE] -> exclusive in-place ----------------
__global__ void scan_partial_kernel(const int* __restrict__ src, int* __restrict__ partial, int n) {
    int t = threadIdx.x;
    int g = blockIdx.x * SCAN_B + t;
    int v = (g < n) ? src[g] : 0;
    for (int m = 1; m < 64; m <<= 1) v += __shfl_xor(v, m);
    __shared__ int ws[16];
    if ((t & 63) == 0) ws[t >> 6] = v;
    __syncthreads();
    if (t < 16) {
        int s = ws[t];
        for (int m = 1; m < 16; m <<= 1) s += __shfl_xor(s, m);
        if (t == 0) partial[blockIdx.x] = s;
    }
}

__global__ void scan_base_kernel(int* __restrict__ partial, int nb, int chunks) {
    int l = threadIdx.x;
    int carry = 0;
    for (int c = 0; c < chunks; c++) {
        int idx = c * 64 + l;
        int v = (idx < nb) ? partial[idx] : 0;
        int inc = v;
        for (int m = 1; m < 64; m <<= 1) {
            int t = __shfl_up(inc, m);
            if (l >= m) inc += t;
        }
        int excl = inc - v + carry;
        if (idx < nb) partial[idx] = excl;
        carry += __shfl(inc, 63);
    }
}

__global__ void scan_apply_kernel(int* __restrict__ data, const int* __restrict__ partial, int n) {
    __shared__ int lds[SCAN_B];
    int t = threadIdx.x;
    int g = blockIdx.x * SCAN_B + t;
    int v = (g < n) ? data[g] : 0;
    int val = v;
    lds[t] = val;
    __syncthreads();
    for (int o = 1; o < SCAN_B; o <<= 1) {
        int add = (t >= o) ? lds[t - o] : 0;
        __syncthreads();
        val += add;
        lds[t] = val;
        __syncthreads();
    }
    if (g < n) data[g] = partial[blockIdx.x] + val - v;  // exclusive
}

// ---------------- pass 2: rank-based partition into bucket-grouped staging ----------------
__global__ __launch_bounds__(256) void partition_kernel(const int* __restrict__ row,
                                                        const int* __restrict__ col,
                                                        const int* __restrict__ hist,
                                                        unsigned* __restrict__ staging) {
    __shared__ int base[NBK];
    __shared__ int cnt[NBK];
    int t = threadIdx.x;
    for (int i = t; i < NBK; i += 256) { base[i] = hist[i * NT + blockIdx.x]; cnt[i] = 0; }
    __syncthreads();
    int e0 = blockIdx.x * TILE;
    int e1 = e0 + TILE; if (e1 > N_EDGES) e1 = N_EDGES;
    for (int i = e0 + t; i < e1; i += 256) {
        int c = col[i];
        int b = c >> BK_BITS;
        int r = atomicAdd(&cnt[b], 1);
        staging[base[b] + r] = ((unsigned)(c & (BK_NODES - 1)) << 18) | (unsigned)row[i];
    }
}

// ---------------- pass 3: per-bucket node offsets + dinv + final CSR ----------------
__global__ __launch_bounds__(512) void fill3_kernel(const int* __restrict__ hist,
                                                    const unsigned* __restrict__ staging,
                                                    int* __restrict__ off,
                                                    float* __restrict__ dinv,
                                                    int* __restrict__ csr_row) {
    __shared__ int cnt[BK_NODES];
    __shared__ int lds[BK_NODES];
    int b = blockIdx.x;
    int t = threadIdx.x;
    int node0 = b << BK_BITS;
    int bstart = hist[b * NT];
    int bend = (b + 1 < NBK) ? hist[(b + 1) * NT] : N_EDGES;
    cnt[t] = 0;
    __syncthreads();
    for (int i = bstart + t; i < bend; i += 512) atomicAdd(&cnt[staging[i] >> 18], 1);
    __syncthreads();
    int v = cnt[t];
    int val = v;
    lds[t] = val;
    __syncthreads();
    for (int o = 1; o < BK_NODES; o <<= 1) {
        int add = (t >= o) ? lds[t - o] : 0;
        __syncthreads();
        val += add;
        lds[t] = val;
        __syncthreads();
    }
    int cursor = bstart + val - v;   // exclusive
    int node = node0 + t;
    if (node < NUM_NODES) {
        off[node] = cursor;
        dinv[node] = (v > 0) ? rsqrtf((float)v) : 0.f;
    }
    cnt[t] = cursor;
    __syncthreads();
    for (int i = bstart + t; i < bend; i += 512) {
        unsigned s = staging[i];
        int pos = atomicAdd(&cnt[s >> 18], 1);
        csr_row[pos] = (int)(s & 0x3FFFFu);
    }
    if (b == 0 && t == 0) off[NUM_NODES] = N_EDGES;
}

// ---------------- mark + compact the ~39K nodes the loss actually touches ------------
__global__ void flag_kernel(const int* __restrict__ u, const int* __restrict__ v,
                            const int* __restrict__ n, char* __restrict__ flags) {
    int i = blockIdx.x * blockDim.x + threadIdx.x;
    if (i >= NLIST) return;
    int id;
    if (i < BATCH) id = u[i];
    else if (i < 2 * BATCH) id = v[i - BATCH];
    else id = n[i - 2 * BATCH];
    flags[id] = 1;
}

__global__ void compact_kernel(const char* __restrict__ flags, int* __restrict__ list,
                               int* __restrict__ count) {
    int i = blockIdx.x * blockDim.x + threadIdx.x;
    if (i < NUM_NODES && flags[i]) {
        int pos = atomicAdd(count, 1);
        list[pos] = i;
    }
}

// ---------------- conv (full graph): y[c] = dinv[c] * sum dinv[row]*x[row] ----------------
__global__ __launch_bounds__(256) void conv_kernel(const int* __restrict__ off,
                                                   const int* __restrict__ csr_row,
                                                   const float* __restrict__ dinv,
                                                   const float* __restrict__ x,
                                                   float* __restrict__ y) {
    int wid = (blockIdx.x * blockDim.x + threadIdx.x) >> 6;
    int lane = threadIdx.x & 63;
    if (wid >= NUM_NODES) return;
    int start = off[wid];
    int end = off[wid + 1];
    float acc = 0.f;
    int i = start;
    for (; i + 3 < end; i += 4) {
        int r0 = csr_row[i], r1 = csr_row[i + 1], r2 = csr_row[i + 2], r3 = csr_row[i + 3];
        float d0 = dinv[r0], d1 = dinv[r1], d2 = dinv[r2], d3 = dinv[r3];
        float v0 = x[(size_t)r0 * DIM + lane];
        float v1 = x[(size_t)r1 * DIM + lane];
        float v2 = x[(size_t)r2 * DIM + lane];
        float v3 = x[(size_t)r3 * DIM + lane];
        acc += d0 * v0 + d1 * v1 + d2 * v2 + d3 * v3;
    }
    for (; i < end; ++i) {
        int r0 = csr_row[i];
        acc += dinv[r0] * x[(size_t)r0 * DIM + lane];
    }
    y[(size_t)wid * DIM + lane] = acc * dinv[wid];
}

// ---------------- conv restricted to listed nodes ----------------
__global__ __launch_bounds__(256) void conv_list_kernel(const int* __restrict__ off,
                                                        const int* __restrict__ csr_row,
                                                        const float* __restrict__ dinv,
                                                        const float* __restrict__ x,
                                                        float* __restrict__ y,
                                                        const int* __restrict__ list,
                                                        const int* __restrict__ count) {
    int li = (blockIdx.x * blockDim.x + threadIdx.x) >> 6;
    int lane = threadIdx.x & 63;
    if (li >= *count) return;
    int wid = list[li];
    int start = off[wid];
    int end = off[wid + 1];
    float acc = 0.f;
    int i = start;
    for (; i + 3 < end; i += 4) {
        int r0 = csr_row[i], r1 = csr_row[i + 1], r2 = csr_row[i + 2], r3 = csr_row[i + 3];
        float d0 = dinv[r0], d1 = dinv[r1], d2 = dinv[r2], d3 = dinv[r3];
        float v0 = x[(size_t)r0 * DIM + lane];
        float v1 = x[(size_t)r1 * DIM + lane];
        float v2 = x[(size_t)r2 * DIM + lane];
        float v3 = x[(size_t)r3 * DIM + lane];
        acc += d0 * v0 + d1 * v1 + d2 * v2 + d3 * v3;
    }
    for (; i < end; ++i) {
        int r0 = csr_row[i];
        acc += dinv[r0] * x[(size_t)r0 * DIM + lane];
    }
    y[(size_t)wid * DIM + lane] = acc * dinv[wid];
}

// ---------------- fused node-wise over listed nodes; wave-independent ----------------
__global__ __launch_bounds__(512) void fuse_kernel(
    const float* __restrict__ E, const float* __restrict__ E2,
    const float* __restrict__ W0, const float* __restrict__ b0,
    const float* __restrict__ W1, const float* __restrict__ b1,
    const float* __restrict__ AW, const float* __restrict__ ab,
    const float* __restrict__ qW,
    const float* x1, const float* x2, float* Z,
    const int* __restrict__ list, const int* __restrict__ count) {
    __shared__ __align__(16) float W0q[4096];
    __shared__ __align__(16) float W1q[4096];
    __shared__ __align__(16) float AWq[4096];
    __shared__ float bb0[64], bb1[64], bab[64], qb[64];
    __shared__ __align__(16) float xbuf[8][64];
    __shared__ __align__(16) float hbuf[8][64];
    __shared__ __align__(16) float zpb[8][64];
    __shared__ __align__(16) float znb[8][64];

    int t = threadIdx.x;
    for (int idx = t; idx < 4096; idx += 512) {
        int j = idx >> 6, k = idx & 63;
        int dst = (k >> 2) * 256 + j * 4 + (k & 3);
        W0q[dst] = W0[idx];
        W1q[dst] = W1[idx];
        AWq[dst] = AW[idx];
    }
    if (t < 64) { bb0[t] = b0[t]; bb1[t] = b1[t]; bab[t] = ab[t]; qb[t] = qW[t]; }
    __syncthreads();   // weights staged once; the node loop below is wave-local

    const int lane = t & 63, w = t >> 6;
    const int cnt = *count;
    for (int li = blockIdx.x * 8 + w; li < cnt; li += gridDim.x * 8) {
        int nd = list[li];
        size_t base = (size_t)nd * DIM + lane;
        float zp = (E[base] + x1[base] + x2[base]) * (1.f / 3.f);
        float e2v = E2[base];
        zpb[w][lane] = zp;
        xbuf[w][lane] = e2v;
        __builtin_amdgcn_wave_barrier();   // wave-local LDS ordering (lgkmcnt handles data)

        float s = bb0[lane];
#pragma unroll
        for (int k4 = 0; k4 < 16; k4++) {
            float4 wq = *(const float4*)&W0q[k4 * 256 + lane * 4];
            float4 xq = *(const float4*)&xbuf[w][k4 * 4];
            s += wq.x * xq.x + wq.y * xq.y + wq.z * xq.z + wq.w * xq.w;
        }
        float h = fmaxf(s, 0.f);
        hbuf[w][lane] = h;
        __builtin_amdgcn_wave_barrier();

        s = bb1[lane];
#pragma unroll
        for (int k4 = 0; k4 < 16; k4++) {
            float4 wq = *(const float4*)&W1q[k4 * 256 + lane * 4];
            float4 xq = *(const float4*)&hbuf[w][k4 * 4];
            s += wq.x * xq.x + wq.y * xq.y + wq.z * xq.z + wq.w * xq.w;
        }
        float zn = fmaxf(s, 0.f);
        znb[w][lane] = zn;
        __builtin_amdgcn_wave_barrier();

        float sp = bab[lane], sn = bab[lane];
#pragma unroll
        for (int k4 = 0; k4 < 16; k4++) {
            float4 wq = *(const float4*)&AWq[k4 * 256 + lane * 4];
            float4 zq = *(const float4*)&zpb[w][k4 * 4];
            float4 nq = *(const float4*)&znb[w][k4 * 4];
            sp += wq.x * zq.x + wq.y * zq.y + wq.z * zq.z + wq.w * zq.w;
            sn += wq.x * nq.x + wq.y * nq.y + wq.z * nq.z + wq.w * nq.w;
        }
        float tp = tanhf(sp) * qb[lane];
        float tn = tanhf(sn) * qb[lane];
        for (int m = 1; m < 64; m <<= 1) {
            tp += __shfl_xor(tp, m);
            tn += __shfl_xor(tn, m);
        }
        float mx = fmaxf(tp, tn);
        float ep = expf(tp - mx), en = expf(tn - mx);
        float inv = 1.f / (ep + en);
        Z[base] = (ep * zp + en * zn) * inv;
        __builtin_amdgcn_wave_barrier();
    }
}

// ---------------- loss ----------------
__global__ __launch_bounds__(256) void loss_kernel(const float* __restrict__ Z,
                                                   const float* __restrict__ wv,
                                                   const int* __restrict__ u,
                                                   const int* __restrict__ v,
                                                   const int* __restrict__ n,
                                                   float* __restrict__ out) {
    int wid = (blockIdx.x * blockDim.x + threadIdx.x) >> 6;
    int lane = threadIdx.x & 63;
    if (wid >= BATCH) return;
    float uu = Z[(size_t)u[wid] * DIM + lane];
    float vv = Z[(size_t)v[wid] * DIM + lane];
    float pos = uu * vv;
    for (int m = 1; m < 64; m <<= 1) pos += __shfl_xor(pos, m);
    float reg = uu * uu + vv * vv;
    float wval = wv[wid];
    float sgn = (wval > 0.f ? 1.f : 0.f) - (wval < 0.f ? 1.f : 0.f);
    float coef = -0.5f * sgn + 1.5f;
    float cp = coef * pos;
    float sb = 0.f;
    for (int k = 0; k < N_NEGS; k++) {
        int nid = n[wid * N_NEGS + k];
        float nn = Z[(size_t)nid * DIM + lane];
        float d = uu * nn;
        for (int m = 1; m < 64; m <<= 1) d += __shfl_xor(d, m);
        reg += nn * nn;
        float x = cp - d;
        float ls = (x >= 0.f) ? -log1pf(expf(-x)) : (x - log1pf(expf(x)));
        sb += ls;
    }
    for (int m = 1; m < 64; m <<= 1) reg += __shfl_xor(reg, m);
    if (lane == 0) atomicAdd(out, -sb + REG_COEF * reg);
}

extern "C" void kernel_launch(void* const* d_in, const int* in_sizes, int n_in,
                              void* d_out, int out_size, void* d_ws, size_t ws_size,
                              hipStream_t stream) {
    const float* E  = (const float*)d_in[0];
    const float* E2 = (const float*)d_in[1];
    const float* W0 = (const float*)d_in[2];
    const float* b0 = (const float*)d_in[3];
    const float* W1 = (const float*)d_in[4];
    const float* b1 = (const float*)d_in[5];
    const float* AW = (const float*)d_in[6];
    const float* ab = (const float*)d_in[7];
    const float* qW = (const float*)d_in[8];
    const float* wv = (const float*)d_in[9];
    const int* ei   = (const int*)d_in[10];
    const int* uu   = (const int*)d_in[11];
    const int* vv   = (const int*)d_in[12];
    const int* nn   = (const int*)d_in[13];
    const int* row = ei;
    const int* col = ei + N_EDGES;

    char* ws = (char*)d_ws;
    size_t p = 0;
    auto align_up = [](size_t x) { return (x + 255) & ~(size_t)255; };
    int* off      = (int*)(ws + p); p = align_up(p + (size_t)(NUM_NODES + 1) * 4);
    float* dinv   = (float*)(ws + p); p = align_up(p + (size_t)NUM_NODES * 4);
    int* hist     = (int*)(ws + p); p = align_up(p + (size_t)HSIZE * 4);
    int* partial  = (int*)(ws + p); p = align_up(p + (size_t)NB2 * 4);
    int* csr_row  = (int*)(ws + p); p = align_up(p + (size_t)N_EDGES * 4);
    char* flags   = (char*)(ws + p); p = align_up(p + (size_t)NUM_NODES);
    int* list     = (int*)(ws + p); p = align_up(p + (size_t)NLIST * 4);
    int* count    = (int*)(ws + p); p = align_up(p + 4);
    float* x1     = (float*)(ws + p); p = align_up(p + (size_t)NUM_NODES * DIM * 4);
    float* x2     = (float*)(ws + p); p = align_up(p + (size_t)NUM_NODES * DIM * 4);
    float* Z = x1;                      // alias: fuse reads x1[nd] then writes Z[nd] same thread
    unsigned* staging = (unsigned*)x2;  // alias: staging consumed before conv2 writes x2

    hipMemsetAsync(d_out, 0, sizeof(float), stream);
    hipMemsetAsync(flags, 0, (size_t)NUM_NODES, stream);
    hipMemsetAsync(count, 0, 4, stream);

    histo_kernel<<<NT, 256, 0, stream>>>(col, hist);
    scan_partial_kernel<<<NB2, SCAN_B, 0, stream>>>(hist, partial, HSIZE);
    scan_base_kernel<<<1, 64, 0, stream>>>(partial, NB2, 2);
    scan_apply_kernel<<<NB2, SCAN_B, 0, stream>>>(hist, partial, HSIZE);
    partition_kernel<<<NT, 256, 0, stream>>>(row, col, hist, staging);
    fill3_kernel<<<NBK, 512, 0, stream>>>(hist, staging, off, dinv, csr_row);

    flag_kernel<<<(NLIST + 255) / 256, 256, 0, stream>>>(uu, vv, nn, flags);
    compact_kernel<<<(NUM_NODES + 255) / 256, 256, 0, stream>>>(flags, list, count);

    conv_kernel<<<NUM_NODES / 4, 256, 0, stream>>>(off, csr_row, dinv, E, x1);
    conv_list_kernel<<<(NLIST + 3) / 4, 256, 0, stream>>>(off, csr_row, dinv, x1, x2, list, count);

    fuse_kernel<<<1024, 512, 0, stream>>>(E, E2, W0, b0, W1, b1, AW, ab, qW, x1, x2, Z, list, count);

    loss_kernel<<<BATCH * 64 / 256, 256, 0, stream>>>(Z, wv, uu, vv, nn, (float*)d_out);
}

// Round 5
// 380.380 us; speedup vs baseline: 3.6828x; 1.0626x over previous
//
#include <hip/hip_runtime.h>
#include <math.h>

#define NUM_NODES 150000
#define DIM 64
#define N_EDGES 3200000
#define BATCH 1024
#define N_NEGS 40
#define REG_COEF 1e-4f

#define BK_BITS 9
#define BK_NODES 512
#define NBK ((NUM_NODES + BK_NODES - 1) >> BK_BITS)      // 293
#define TILE 8192
#define NT ((N_EDGES + TILE - 1) / TILE)                 // 391
#define HSIZE (NBK * NT)                                 // 114563
#define SCAN_B 1024
#define NB2 ((HSIZE + SCAN_B - 1) / SCAN_B)              // 112
#define NLIST (BATCH * (N_NEGS + 2))                     // 43008

// ---------------- pass 1: per-tile bucket histogram ----------------
__global__ __launch_bounds__(256) void histo_kernel(const int* __restrict__ col,
                                                    int* __restrict__ hist) {
    __shared__ int h[NBK];
    int t = threadIdx.x;
    for (int i = t; i < NBK; i += 256) h[i] = 0;
    __syncthreads();
    int e0 = blockIdx.x * TILE;
    int e1 = e0 + TILE; if (e1 > N_EDGES) e1 = N_EDGES;
    for (int i = e0 + t; i < e1; i += 256) atomicAdd(&h[col[i] >> BK_BITS], 1);
    __syncthreads();
    for (int i = t; i < NBK; i += 256) hist[i * NT + blockIdx.x] = h[i];
}

// ---------------- scan (3 kernels) over hist[HSIZE] -> exclusive in-place ----------------
__global__ void scan_partial_kernel(const int* __restrict__ src, int* __restrict__ partial, int n) {
    int t = threadIdx.x;
    int g = blockIdx.x * SCAN_B + t;
    int v = (g < n) ? src[g] : 0;
    for (int m = 1; m < 64; m <<= 1) v += __shfl_xor(v, m);
    __shared__ int ws[16];
    if ((t & 63) == 0) ws[t >> 6] = v;
    __syncthreads();
    if (t < 16) {
        int s = ws[t];
        for (int m = 1; m < 16; m <<= 1) s += __shfl_xor(s, m);
        if (t == 0) partial[blockIdx.x] = s;
    }
}

__global__ void scan_base_kernel(int* __restrict__ partial, int nb, int chunks) {
    int l = threadIdx.x;
    int carry = 0;
    for (int c = 0; c < chunks; c++) {
        int idx = c * 64 + l;
        int v = (idx < nb) ? partial[idx] : 0;
        int inc = v;
        for (int m = 1; m < 64; m <<= 1) {
            int t = __shfl_up(inc, m);
            if (l >= m) inc += t;
        }
        int excl = inc - v + carry;
        if (idx < nb) partial[idx] = excl;
        carry += __shfl(inc, 63);
    }
}

__global__ void scan_apply_kernel(int* __restrict__ data, const int* __restrict__ partial, int n) {
    __shared__ int lds[SCAN_B];
    int t = threadIdx.x;
    int g = blockIdx.x * SCAN_B + t;
    int v = (g < n) ? data[g] : 0;
    int val = v;
    lds[t] = val;
    __syncthreads();
    for (int o = 1; o < SCAN_B; o <<= 1) {
        int add = (t >= o) ? lds[t - o] : 0;
        __syncthreads();
        val += add;
        lds[t] = val;
        __syncthreads();
    }
    if (g < n) data[g] = partial[blockIdx.x] + val - v;  // exclusive
}

// ---------------- pass 2: rank-based partition into bucket-grouped staging ----------------
__global__ __launch_bounds__(256) void partition_kernel(const int* __restrict__ row,
                                                        const int* __restrict__ col,
                                                        const int* __restrict__ hist,
                                                        unsigned* __restrict__ staging) {
    __shared__ int base[NBK];
    __shared__ int cnt[NBK];
    int t = threadIdx.x;
    for (int i = t; i < NBK; i += 256) { base[i] = hist[i * NT + blockIdx.x]; cnt[i] = 0; }
    __syncthreads();
    int e0 = blockIdx.x * TILE;
    int e1 = e0 + TILE; if (e1 > N_EDGES) e1 = N_EDGES;
    for (int i = e0 + t; i < e1; i += 256) {
        int c = col[i];
        int b = c >> BK_BITS;
        int r = atomicAdd(&cnt[b], 1);
        staging[base[b] + r] = ((unsigned)(c & (BK_NODES - 1)) << 18) | (unsigned)row[i];
    }
}

// ---------------- pass 3: per-bucket offsets + dinv + sq + CSR + pre-scaled fp16 E ------
__global__ __launch_bounds__(512) void fill3_kernel(const int* __restrict__ hist,
                                                    const unsigned* __restrict__ staging,
                                                    const float* __restrict__ E,
                                                    int* __restrict__ off,
                                                    float* __restrict__ dinv,
                                                    float* __restrict__ sq,
                                                    int* __restrict__ csr_row,
                                                    _Float16* __restrict__ xnE) {
    __shared__ int cnt[BK_NODES];
    __shared__ int lds[BK_NODES];
    __shared__ float sdinv[BK_NODES];
    int b = blockIdx.x;
    int t = threadIdx.x;
    int node0 = b << BK_BITS;
    int bstart = hist[b * NT];
    int bend = (b + 1 < NBK) ? hist[(b + 1) * NT] : N_EDGES;
    cnt[t] = 0;
    __syncthreads();
    for (int i = bstart + t; i < bend; i += 512) atomicAdd(&cnt[staging[i] >> 18], 1);
    __syncthreads();
    int v = cnt[t];
    int val = v;
    lds[t] = val;
    __syncthreads();
    for (int o = 1; o < BK_NODES; o <<= 1) {
        int add = (t >= o) ? lds[t - o] : 0;
        __syncthreads();
        val += add;
        lds[t] = val;
        __syncthreads();
    }
    int cursor = bstart + val - v;   // exclusive
    int node = node0 + t;
    float dv = (v > 0) ? rsqrtf((float)v) : 0.f;
    if (node < NUM_NODES) {
        off[node] = cursor;
        dinv[node] = dv;
        sq[node] = sqrtf((float)v);
    }
    sdinv[t] = dv;
    cnt[t] = cursor;
    __syncthreads();
    for (int i = bstart + t; i < bend; i += 512) {
        unsigned s = staging[i];
        int pos = atomicAdd(&cnt[s >> 18], 1);
        csr_row[pos] = (int)(s & 0x3FFFFu);
    }
    // pre-scaled fp16 operand: xnE[node] = dinv[node] * E[node]
    int nvalid = NUM_NODES - node0; if (nvalid > BK_NODES) nvalid = BK_NODES;
    int total = nvalid << 6;
    size_t gbase = (size_t)node0 << 6;
    for (int idx = t; idx < total; idx += 512) {
        float e = E[gbase + idx];
        xnE[gbase + idx] = (_Float16)(sdinv[idx >> 6] * e);
    }
    if (b == 0 && t == 0) off[NUM_NODES] = N_EDGES;
}

// ---------------- mark + compact the ~39K nodes the loss actually touches ------------
__global__ void flag_kernel(const int* __restrict__ u, const int* __restrict__ v,
                            const int* __restrict__ n, char* __restrict__ flags) {
    int i = blockIdx.x * blockDim.x + threadIdx.x;
    if (i >= NLIST) return;
    int id;
    if (i < BATCH) id = u[i];
    else if (i < 2 * BATCH) id = v[i - BATCH];
    else id = n[i - 2 * BATCH];
    flags[id] = 1;
}

__global__ void compact_kernel(const char* __restrict__ flags, int* __restrict__ list,
                               int* __restrict__ count) {
    int i = blockIdx.x * blockDim.x + threadIdx.x;
    if (i < NUM_NODES && flags[i]) {
        int pos = atomicAdd(count, 1);
        list[pos] = i;
    }
}

// ---- conv layer 1 (full graph): xn1[c] = fp16( dinv[c]^2 * sum_in xnE[row] ) ----------
__global__ __launch_bounds__(256) void conv1_kernel(const int* __restrict__ off,
                                                    const int* __restrict__ csr_row,
                                                    const float* __restrict__ dinv,
                                                    const _Float16* __restrict__ xh,
                                                    _Float16* __restrict__ yh) {
    int wid = (blockIdx.x * blockDim.x + threadIdx.x) >> 6;
    int lane = threadIdx.x & 63;
    if (wid >= NUM_NODES) return;
    int start = off[wid];
    int end = off[wid + 1];
    float acc = 0.f;
    int i = start;
    for (; i + 7 < end; i += 8) {
        int r[8];
        float v[8];
#pragma unroll
        for (int k = 0; k < 8; k++) r[k] = csr_row[i + k];
#pragma unroll
        for (int k = 0; k < 8; k++) v[k] = (float)xh[((size_t)r[k] << 6) + lane];
#pragma unroll
        for (int k = 0; k < 8; k++) acc += v[k];
    }
    for (; i < end; ++i) acc += (float)xh[((size_t)csr_row[i] << 6) + lane];
    float dv = dinv[wid];
    yh[((size_t)wid << 6) + lane] = (_Float16)(dv * dv * acc);
}

// ---- conv layer 2 (listed nodes only): x2[c] = dinv[c] * sum_in xn1[row] ------------
__global__ __launch_bounds__(256) void conv2_kernel(const int* __restrict__ off,
                                                    const int* __restrict__ csr_row,
                                                    const float* __restrict__ dinv,
                                                    const _Float16* __restrict__ xh,
                                                    float* __restrict__ x2,
                                                    const int* __restrict__ list,
                                                    const int* __restrict__ count) {
    int li = (blockIdx.x * blockDim.x + threadIdx.x) >> 6;
    int lane = threadIdx.x & 63;
    if (li >= *count) return;
    int wid = list[li];
    int start = off[wid];
    int end = off[wid + 1];
    float acc = 0.f;
    int i = start;
    for (; i + 7 < end; i += 8) {
        int r[8];
        float v[8];
#pragma unroll
        for (int k = 0; k < 8; k++) r[k] = csr_row[i + k];
#pragma unroll
        for (int k = 0; k < 8; k++) v[k] = (float)xh[((size_t)r[k] << 6) + lane];
#pragma unroll
        for (int k = 0; k < 8; k++) acc += v[k];
    }
    for (; i < end; ++i) acc += (float)xh[((size_t)csr_row[i] << 6) + lane];
    x2[((size_t)wid << 6) + lane] = dinv[wid] * acc;
}

// ---------------- fused node-wise over listed nodes; wave-independent ----------------
__global__ __launch_bounds__(512) void fuse_kernel(
    const float* __restrict__ E, const float* __restrict__ E2,
    const float* __restrict__ W0, const float* __restrict__ b0,
    const float* __restrict__ W1, const float* __restrict__ b1,
    const float* __restrict__ AW, const float* __restrict__ ab,
    const float* __restrict__ qW,
    const _Float16* __restrict__ xn1, const float* __restrict__ sq,
    const float* x2, float* Z,
    const int* __restrict__ list, const int* __restrict__ count) {
    __shared__ __align__(16) float W0q[4096];
    __shared__ __align__(16) float W1q[4096];
    __shared__ __align__(16) float AWq[4096];
    __shared__ float bb0[64], bb1[64], bab[64], qb[64];
    __shared__ __align__(16) float xbuf[8][64];
    __shared__ __align__(16) float hbuf[8][64];
    __shared__ __align__(16) float zpb[8][64];
    __shared__ __align__(16) float znb[8][64];

    int t = threadIdx.x;
    for (int idx = t; idx < 4096; idx += 512) {
        int j = idx >> 6, k = idx & 63;
        int dst = (k >> 2) * 256 + j * 4 + (k & 3);
        W0q[dst] = W0[idx];
        W1q[dst] = W1[idx];
        AWq[dst] = AW[idx];
    }
    if (t < 64) { bb0[t] = b0[t]; bb1[t] = b1[t]; bab[t] = ab[t]; qb[t] = qW[t]; }
    __syncthreads();   // weights staged once; the node loop below is wave-local

    const int lane = t & 63, w = t >> 6;
    const int cnt = *count;
    for (int li = blockIdx.x * 8 + w; li < cnt; li += gridDim.x * 8) {
        int nd = list[li];
        size_t base = ((size_t)nd << 6) + lane;
        float x1v = sq[nd] * (float)xn1[base];
        float zp = (E[base] + x1v + x2[base]) * (1.f / 3.f);
        float e2v = E2[base];
        zpb[w][lane] = zp;
        xbuf[w][lane] = e2v;
        __builtin_amdgcn_wave_barrier();

        float s = bb0[lane];
#pragma unroll
        for (int k4 = 0; k4 < 16; k4++) {
            float4 wq = *(const float4*)&W0q[k4 * 256 + lane * 4];
            float4 xq = *(const float4*)&xbuf[w][k4 * 4];
            s += wq.x * xq.x + wq.y * xq.y + wq.z * xq.z + wq.w * xq.w;
        }
        float h = fmaxf(s, 0.f);
        hbuf[w][lane] = h;
        __builtin_amdgcn_wave_barrier();

        s = bb1[lane];
#pragma unroll
        for (int k4 = 0; k4 < 16; k4++) {
            float4 wq = *(const float4*)&W1q[k4 * 256 + lane * 4];
            float4 xq = *(const float4*)&hbuf[w][k4 * 4];
            s += wq.x * xq.x + wq.y * xq.y + wq.z * xq.z + wq.w * xq.w;
        }
        float zn = fmaxf(s, 0.f);
        znb[w][lane] = zn;
        __builtin_amdgcn_wave_barrier();

        float sp = bab[lane], sn = bab[lane];
#pragma unroll
        for (int k4 = 0; k4 < 16; k4++) {
            float4 wq = *(const float4*)&AWq[k4 * 256 + lane * 4];
            float4 zq = *(const float4*)&zpb[w][k4 * 4];
            float4 nq = *(const float4*)&znb[w][k4 * 4];
            sp += wq.x * zq.x + wq.y * zq.y + wq.z * zq.z + wq.w * zq.w;
            sn += wq.x * nq.x + wq.y * nq.y + wq.z * nq.z + wq.w * nq.w;
        }
        float tp = tanhf(sp) * qb[lane];
        float tn = tanhf(sn) * qb[lane];
        for (int m = 1; m < 64; m <<= 1) {
            tp += __shfl_xor(tp, m);
            tn += __shfl_xor(tn, m);
        }
        float mx = fmaxf(tp, tn);
        float ep = expf(tp - mx), en = expf(tn - mx);
        float inv = 1.f / (ep + en);
        Z[base] = (ep * zp + en * zn) * inv;
        __builtin_amdgcn_wave_barrier();
    }
}

// ---------------- loss ----------------
__global__ __launch_bounds__(256) void loss_kernel(const float* __restrict__ Z,
                                                   const float* __restrict__ wv,
                                                   const int* __restrict__ u,
                                                   const int* __restrict__ v,
                                                   const int* __restrict__ n,
                                                   float* __restrict__ out) {
    int wid = (blockIdx.x * blockDim.x + threadIdx.x) >> 6;
    int lane = threadIdx.x & 63;
    if (wid >= BATCH) return;
    float uu = Z[(size_t)u[wid] * DIM + lane];
    float vv = Z[(size_t)v[wid] * DIM + lane];
    float pos = uu * vv;
    for (int m = 1; m < 64; m <<= 1) pos += __shfl_xor(pos, m);
    float reg = uu * uu + vv * vv;
    float wval = wv[wid];
    float sgn = (wval > 0.f ? 1.f : 0.f) - (wval < 0.f ? 1.f : 0.f);
    float coef = -0.5f * sgn + 1.5f;
    float cp = coef * pos;
    float sb = 0.f;
    for (int k = 0; k < N_NEGS; k++) {
        int nid = n[wid * N_NEGS + k];
        float nn = Z[(size_t)nid * DIM + lane];
        float d = uu * nn;
        for (int m = 1; m < 64; m <<= 1) d += __shfl_xor(d, m);
        reg += nn * nn;
        float x = cp - d;
        float ls = (x >= 0.f) ? -log1pf(expf(-x)) : (x - log1pf(expf(x)));
        sb += ls;
    }
    for (int m = 1; m < 64; m <<= 1) reg += __shfl_xor(reg, m);
    if (lane == 0) atomicAdd(out, -sb + REG_COEF * reg);
}

extern "C" void kernel_launch(void* const* d_in, const int* in_sizes, int n_in,
                              void* d_out, int out_size, void* d_ws, size_t ws_size,
                              hipStream_t stream) {
    const float* E  = (const float*)d_in[0];
    const float* E2 = (const float*)d_in[1];
    const float* W0 = (const float*)d_in[2];
    const float* b0 = (const float*)d_in[3];
    const float* W1 = (const float*)d_in[4];
    const float* b1 = (const float*)d_in[5];
    const float* AW = (const float*)d_in[6];
    const float* ab = (const float*)d_in[7];
    const float* qW = (const float*)d_in[8];
    const float* wv = (const float*)d_in[9];
    const int* ei   = (const int*)d_in[10];
    const int* uu   = (const int*)d_in[11];
    const int* vv   = (const int*)d_in[12];
    const int* nn   = (const int*)d_in[13];
    const int* row = ei;
    const int* col = ei + N_EDGES;

    char* ws = (char*)d_ws;
    size_t p = 0;
    auto align_up = [](size_t x) { return (x + 255) & ~(size_t)255; };
    int* off        = (int*)(ws + p); p = align_up(p + (size_t)(NUM_NODES + 1) * 4);
    float* dinv     = (float*)(ws + p); p = align_up(p + (size_t)NUM_NODES * 4);
    float* sq       = (float*)(ws + p); p = align_up(p + (size_t)NUM_NODES * 4);
    int* hist       = (int*)(ws + p); p = align_up(p + (size_t)HSIZE * 4);
    int* partial    = (int*)(ws + p); p = align_up(p + (size_t)NB2 * 4);
    int* csr_row    = (int*)(ws + p); p = align_up(p + (size_t)N_EDGES * 4);
    char* flags     = (char*)(ws + p); p = align_up(p + (size_t)NUM_NODES);
    int* list       = (int*)(ws + p); p = align_up(p + (size_t)NLIST * 4);
    int* count      = (int*)(ws + p); p = align_up(p + 4);
    _Float16* xnE   = (_Float16*)(ws + p); p = align_up(p + (size_t)NUM_NODES * DIM * 2);
    _Float16* xn1   = (_Float16*)(ws + p); p = align_up(p + (size_t)NUM_NODES * DIM * 2);
    float* x2f      = (float*)(ws + p); p = align_up(p + (size_t)NUM_NODES * DIM * 4);
    float* Z = x2f;                      // alias: fuse reads x2f[nd] then writes Z[nd] same thread
    unsigned* staging = (unsigned*)x2f;  // alias: staging consumed by fill3 before conv2 writes x2f

    hipMemsetAsync(d_out, 0, sizeof(float), stream);
    hipMemsetAsync(flags, 0, (size_t)NUM_NODES, stream);
    hipMemsetAsync(count, 0, 4, stream);

    histo_kernel<<<NT, 256, 0, stream>>>(col, hist);
    scan_partial_kernel<<<NB2, SCAN_B, 0, stream>>>(hist, partial, HSIZE);
    scan_base_kernel<<<1, 64, 0, stream>>>(partial, NB2, 2);
    scan_apply_kernel<<<NB2, SCAN_B, 0, stream>>>(hist, partial, HSIZE);
    partition_kernel<<<NT, 256, 0, stream>>>(row, col, hist, staging);
    fill3_kernel<<<NBK, 512, 0, stream>>>(hist, staging, E, off, dinv, sq, csr_row, xnE);

    flag_kernel<<<(NLIST + 255) / 256, 256, 0, stream>>>(uu, vv, nn, flags);
    compact_kernel<<<(NUM_NODES + 255) / 256, 256, 0, stream>>>(flags, list, count);

    conv1_kernel<<<NUM_NODES / 4, 256, 0, stream>>>(off, csr_row, dinv, xnE, xn1);
    conv2_kernel<<<(NLIST + 3) / 4, 256, 0, stream>>>(off, csr_row, dinv, xn1, x2f, list, count);

    fuse_kernel<<<1024, 512, 0, stream>>>(E, E2, W0, b0, W1, b1, AW, ab, qW,
                                          xn1, sq, x2f, Z, list, count);

    loss_kernel<<<BATCH * 64 / 256, 256, 0, stream>>>(Z, wv, uu, vv, nn, (float*)d_out);
}

// Round 6
// 370.591 us; speedup vs baseline: 3.7800x; 1.0264x over previous
//
#include <hip/hip_runtime.h>
#include <hip/hip_fp8.h>
#include <math.h>

#define NUM_NODES 150000
#define DIM 64
#define N_EDGES 3200000
#define BATCH 1024
#define N_NEGS 40
#define REG_COEF 1e-4f

#define BK_BITS 9
#define BK_NODES 512
#define NBK ((NUM_NODES + BK_NODES - 1) >> BK_BITS)      // 293
#define TILE 8192
#define NT ((N_EDGES + TILE - 1) / TILE)                 // 391
#define HSIZE (NBK * NT)                                 // 114563
#define SCAN_B 1024
#define NB2 ((HSIZE + SCAN_B - 1) / SCAN_B)              // 112
#define NLIST (BATCH * (N_NEGS + 2))                     // 43008

// ---------------- pass 1: per-tile bucket histogram ----------------
__global__ __launch_bounds__(256) void histo_kernel(const int* __restrict__ col,
                                                    int* __restrict__ hist) {
    __shared__ int h[NBK];
    int t = threadIdx.x;
    for (int i = t; i < NBK; i += 256) h[i] = 0;
    __syncthreads();
    int e0 = blockIdx.x * TILE;
    int e1 = e0 + TILE; if (e1 > N_EDGES) e1 = N_EDGES;
    for (int i = e0 + t; i < e1; i += 256) atomicAdd(&h[col[i] >> BK_BITS], 1);
    __syncthreads();
    for (int i = t; i < NBK; i += 256) hist[i * NT + blockIdx.x] = h[i];
}

// ---------------- scan (3 kernels) over hist[HSIZE] -> exclusive in-place ----------------
__global__ void scan_partial_kernel(const int* __restrict__ src, int* __restrict__ partial, int n) {
    int t = threadIdx.x;
    int g = blockIdx.x * SCAN_B + t;
    int v = (g < n) ? src[g] : 0;
    for (int m = 1; m < 64; m <<= 1) v += __shfl_xor(v, m);
    __shared__ int ws[16];
    if ((t & 63) == 0) ws[t >> 6] = v;
    __syncthreads();
    if (t < 16) {
        int s = ws[t];
        for (int m = 1; m < 16; m <<= 1) s += __shfl_xor(s, m);
        if (t == 0) partial[blockIdx.x] = s;
    }
}

__global__ void scan_base_kernel(int* __restrict__ partial, int nb, int chunks) {
    int l = threadIdx.x;
    int carry = 0;
    for (int c = 0; c < chunks; c++) {
        int idx = c * 64 + l;
        int v = (idx < nb) ? partial[idx] : 0;
        int inc = v;
        for (int m = 1; m < 64; m <<= 1) {
            int t = __shfl_up(inc, m);
            if (l >= m) inc += t;
        }
        int excl = inc - v + carry;
        if (idx < nb) partial[idx] = excl;
        carry += __shfl(inc, 63);
    }
}

__global__ void scan_apply_kernel(int* __restrict__ data, const int* __restrict__ partial, int n) {
    __shared__ int lds[SCAN_B];
    int t = threadIdx.x;
    int g = blockIdx.x * SCAN_B + t;
    int v = (g < n) ? data[g] : 0;
    int val = v;
    lds[t] = val;
    __syncthreads();
    for (int o = 1; o < SCAN_B; o <<= 1) {
        int add = (t >= o) ? lds[t - o] : 0;
        __syncthreads();
        val += add;
        lds[t] = val;
        __syncthreads();
    }
    if (g < n) data[g] = partial[blockIdx.x] + val - v;  // exclusive
}

// ---------------- pass 2: rank-based partition into bucket-grouped staging ----------------
__global__ __launch_bounds__(256) void partition_kernel(const int* __restrict__ row,
                                                        const int* __restrict__ col,
                                                        const int* __restrict__ hist,
                                                        unsigned* __restrict__ staging) {
    __shared__ int base[NBK];
    __shared__ int cnt[NBK];
    int t = threadIdx.x;
    for (int i = t; i < NBK; i += 256) { base[i] = hist[i * NT + blockIdx.x]; cnt[i] = 0; }
    __syncthreads();
    int e0 = blockIdx.x * TILE;
    int e1 = e0 + TILE; if (e1 > N_EDGES) e1 = N_EDGES;
    for (int i = e0 + t; i < e1; i += 256) {
        int c = col[i];
        int b = c >> BK_BITS;
        int r = atomicAdd(&cnt[b], 1);
        staging[base[b] + r] = ((unsigned)(c & (BK_NODES - 1)) << 18) | (unsigned)row[i];
    }
}

// ------ pass 3: per-bucket offsets + dinv + sq + CSR + pre-scaled fp8 E (x16 scale) ------
__global__ __launch_bounds__(512) void fill3_kernel(const int* __restrict__ hist,
                                                    const unsigned* __restrict__ staging,
                                                    const float* __restrict__ E,
                                                    int* __restrict__ off,
                                                    float* __restrict__ dinv,
                                                    float* __restrict__ sq,
                                                    int* __restrict__ csr_row,
                                                    __hip_fp8x4_e4m3* __restrict__ xnE4) {
    __shared__ int cnt[BK_NODES];
    __shared__ int lds[BK_NODES];
    __shared__ float sdinv[BK_NODES];
    int b = blockIdx.x;
    int t = threadIdx.x;
    int node0 = b << BK_BITS;
    int bstart = hist[b * NT];
    int bend = (b + 1 < NBK) ? hist[(b + 1) * NT] : N_EDGES;
    cnt[t] = 0;
    __syncthreads();
    for (int i = bstart + t; i < bend; i += 512) atomicAdd(&cnt[staging[i] >> 18], 1);
    __syncthreads();
    int v = cnt[t];
    int val = v;
    lds[t] = val;
    __syncthreads();
    for (int o = 1; o < BK_NODES; o <<= 1) {
        int add = (t >= o) ? lds[t - o] : 0;
        __syncthreads();
        val += add;
        lds[t] = val;
        __syncthreads();
    }
    int cursor = bstart + val - v;   // exclusive
    int node = node0 + t;
    float dv = (v > 0) ? rsqrtf((float)v) : 0.f;
    if (node < NUM_NODES) {
        off[node] = cursor;
        dinv[node] = dv;
        sq[node] = sqrtf((float)v);
    }
    sdinv[t] = dv;
    cnt[t] = cursor;
    __syncthreads();
    for (int i = bstart + t; i < bend; i += 512) {
        unsigned s = staging[i];
        int pos = atomicAdd(&cnt[s >> 18], 1);
        csr_row[pos] = (int)(s & 0x3FFFFu);
    }
    // pre-scaled fp8 operand: xnE[node] = e4m3( 16 * dinv[node] * E[node] )
    int nvalid = NUM_NODES - node0; if (nvalid > BK_NODES) nvalid = BK_NODES;
    int groups = nvalid << 4;                         // 16 float4-groups per row
    const float4* E4 = (const float4*)E + ((size_t)node0 << 4);
    __hip_fp8x4_e4m3* out4 = xnE4 + ((size_t)node0 << 4);
    for (int gi = t; gi < groups; gi += 512) {
        float4 e = E4[gi];
        float s = 16.f * sdinv[gi >> 4];
        out4[gi] = __hip_fp8x4_e4m3(make_float4(s * e.x, s * e.y, s * e.z, s * e.w));
    }
    if (b == 0 && t == 0) off[NUM_NODES] = N_EDGES;
}

// ---------------- mark + compact the ~39K nodes the loss actually touches ------------
__global__ void flag_kernel(const int* __restrict__ u, const int* __restrict__ v,
                            const int* __restrict__ n, char* __restrict__ flags) {
    int i = blockIdx.x * blockDim.x + threadIdx.x;
    if (i >= NLIST) return;
    int id;
    if (i < BATCH) id = u[i];
    else if (i < 2 * BATCH) id = v[i - BATCH];
    else id = n[i - 2 * BATCH];
    flags[id] = 1;
}

__global__ void compact_kernel(const char* __restrict__ flags, int* __restrict__ list,
                               int* __restrict__ count) {
    int i = blockIdx.x * blockDim.x + threadIdx.x;
    if (i < NUM_NODES && flags[i]) {
        int pos = atomicAdd(count, 1);
        list[pos] = i;
    }
}

// ---- conv layer 1 (full graph, fp8 operand, 4 rows/instruction):
//      xn1[c] = fp16( dinv[c]^2/16 * sum_in 16*dinv*E[row] )
__global__ __launch_bounds__(256) void conv1_kernel(const int* __restrict__ off,
                                                    const int* __restrict__ csr_row,
                                                    const float* __restrict__ dinv,
                                                    const __hip_fp8x4_e4m3* __restrict__ xq,
                                                    _Float16* __restrict__ yh) {
    int wid = (blockIdx.x * blockDim.x + threadIdx.x) >> 6;
    int lane = threadIdx.x & 63;
    if (wid >= NUM_NODES) return;
    int g = lane & 15, q = lane >> 4;
    int start = off[wid];
    int end = off[wid + 1];
    float a0 = 0.f, a1 = 0.f, a2 = 0.f, a3 = 0.f;
    for (int i = start; i < end; i += 4) {
        int iq = i + q;
        float wq = (iq < end) ? 1.f : 0.f;
        int idx = (iq < end) ? iq : (end - 1);   // clamp: dup line dedups in-flight
        int r = csr_row[idx];
        float4 vv = static_cast<float4>(xq[((size_t)r << 4) + g]);
        a0 += wq * vv.x; a1 += wq * vv.y; a2 += wq * vv.z; a3 += wq * vv.w;
    }
    a0 += __shfl_xor(a0, 16); a1 += __shfl_xor(a1, 16);
    a2 += __shfl_xor(a2, 16); a3 += __shfl_xor(a3, 16);
    a0 += __shfl_xor(a0, 32); a1 += __shfl_xor(a1, 32);
    a2 += __shfl_xor(a2, 32); a3 += __shfl_xor(a3, 32);
    if (q == 0) {
        float dv = dinv[wid];
        float s = dv * dv * (1.f / 16.f);
        union { _Float16 h[4]; short4 s4; } u;
        u.h[0] = (_Float16)(s * a0);
        u.h[1] = (_Float16)(s * a1);
        u.h[2] = (_Float16)(s * a2);
        u.h[3] = (_Float16)(s * a3);
        ((short4*)yh)[((size_t)wid << 4) + g] = u.s4;
    }
}

// ---- conv layer 2 (listed nodes, fp16 operand, 4 rows/instruction):
//      x2[c] = dinv[c] * sum_in xn1[row]
__global__ __launch_bounds__(256) void conv2_kernel(const int* __restrict__ off,
                                                    const int* __restrict__ csr_row,
                                                    const float* __restrict__ dinv,
                                                    const _Float16* __restrict__ xh,
                                                    float* __restrict__ x2,
                                                    const int* __restrict__ list,
                                                    const int* __restrict__ count) {
    int li = (blockIdx.x * blockDim.x + threadIdx.x) >> 6;
    int lane = threadIdx.x & 63;
    if (li >= *count) return;
    int wid = list[li];
    int g = lane & 15, q = lane >> 4;
    int start = off[wid];
    int end = off[wid + 1];
    float a0 = 0.f, a1 = 0.f, a2 = 0.f, a3 = 0.f;
    const short4* xh4 = (const short4*)xh;
    for (int i = start; i < end; i += 4) {
        int iq = i + q;
        float wq = (iq < end) ? 1.f : 0.f;
        int idx = (iq < end) ? iq : (end - 1);
        int r = csr_row[idx];
        union { short4 s4; _Float16 h[4]; } u;
        u.s4 = xh4[((size_t)r << 4) + g];
        a0 += wq * (float)u.h[0]; a1 += wq * (float)u.h[1];
        a2 += wq * (float)u.h[2]; a3 += wq * (float)u.h[3];
    }
    a0 += __shfl_xor(a0, 16); a1 += __shfl_xor(a1, 16);
    a2 += __shfl_xor(a2, 16); a3 += __shfl_xor(a3, 16);
    a0 += __shfl_xor(a0, 32); a1 += __shfl_xor(a1, 32);
    a2 += __shfl_xor(a2, 32); a3 += __shfl_xor(a3, 32);
    if (q == 0) {
        float dv = dinv[wid];
        ((float4*)x2)[((size_t)wid << 4) + g] =
            make_float4(dv * a0, dv * a1, dv * a2, dv * a3);
    }
}

// ---------------- fused node-wise over listed nodes; wave-independent ----------------
__global__ __launch_bounds__(512) void fuse_kernel(
    const float* __restrict__ E, const float* __restrict__ E2,
    const float* __restrict__ W0, const float* __restrict__ b0,
    const float* __restrict__ W1, const float* __restrict__ b1,
    const float* __restrict__ AW, const float* __restrict__ ab,
    const float* __restrict__ qW,
    const _Float16* __restrict__ xn1, const float* __restrict__ sq,
    const float* x2, float* Z,
    const int* __restrict__ list, const int* __restrict__ count) {
    __shared__ __align__(16) float W0q[4096];
    __shared__ __align__(16) float W1q[4096];
    __shared__ __align__(16) float AWq[4096];
    __shared__ float bb0[64], bb1[64], bab[64], qb[64];
    __shared__ __align__(16) float xbuf[8][64];
    __shared__ __align__(16) float hbuf[8][64];
    __shared__ __align__(16) float zpb[8][64];
    __shared__ __align__(16) float znb[8][64];

    int t = threadIdx.x;
    for (int idx = t; idx < 4096; idx += 512) {
        int j = idx >> 6, k = idx & 63;
        int dst = (k >> 2) * 256 + j * 4 + (k & 3);
        W0q[dst] = W0[idx];
        W1q[dst] = W1[idx];
        AWq[dst] = AW[idx];
    }
    if (t < 64) { bb0[t] = b0[t]; bb1[t] = b1[t]; bab[t] = ab[t]; qb[t] = qW[t]; }
    __syncthreads();   // weights staged once; the node loop below is wave-local

    const int lane = t & 63, w = t >> 6;
    const int cnt = *count;
    for (int li = blockIdx.x * 8 + w; li < cnt; li += gridDim.x * 8) {
        int nd = list[li];
        size_t base = ((size_t)nd << 6) + lane;
        float x1v = sq[nd] * (float)xn1[base];
        float zp = (E[base] + x1v + x2[base]) * (1.f / 3.f);
        float e2v = E2[base];
        zpb[w][lane] = zp;
        xbuf[w][lane] = e2v;
        __builtin_amdgcn_wave_barrier();

        float s = bb0[lane];
#pragma unroll
        for (int k4 = 0; k4 < 16; k4++) {
            float4 wq = *(const float4*)&W0q[k4 * 256 + lane * 4];
            float4 xq = *(const float4*)&xbuf[w][k4 * 4];
            s += wq.x * xq.x + wq.y * xq.y + wq.z * xq.z + wq.w * xq.w;
        }
        float h = fmaxf(s, 0.f);
        hbuf[w][lane] = h;
        __builtin_amdgcn_wave_barrier();

        s = bb1[lane];
#pragma unroll
        for (int k4 = 0; k4 < 16; k4++) {
            float4 wq = *(const float4*)&W1q[k4 * 256 + lane * 4];
            float4 xq = *(const float4*)&hbuf[w][k4 * 4];
            s += wq.x * xq.x + wq.y * xq.y + wq.z * xq.z + wq.w * xq.w;
        }
        float zn = fmaxf(s, 0.f);
        znb[w][lane] = zn;
        __builtin_amdgcn_wave_barrier();

        float sp = bab[lane], sn = bab[lane];
#pragma unroll
        for (int k4 = 0; k4 < 16; k4++) {
            float4 wq = *(const float4*)&AWq[k4 * 256 + lane * 4];
            float4 zq = *(const float4*)&zpb[w][k4 * 4];
            float4 nq = *(const float4*)&znb[w][k4 * 4];
            sp += wq.x * zq.x + wq.y * zq.y + wq.z * zq.z + wq.w * zq.w;
            sn += wq.x * nq.x + wq.y * nq.y + wq.z * nq.z + wq.w * nq.w;
        }
        float tp = tanhf(sp) * qb[lane];
        float tn = tanhf(sn) * qb[lane];
        for (int m = 1; m < 64; m <<= 1) {
            tp += __shfl_xor(tp, m);
            tn += __shfl_xor(tn, m);
        }
        float mx = fmaxf(tp, tn);
        float ep = expf(tp - mx), en = expf(tn - mx);
        float inv = 1.f / (ep + en);
        Z[base] = (ep * zp + en * zn) * inv;
        __builtin_amdgcn_wave_barrier();
    }
}

// ---------------- loss ----------------
__global__ __launch_bounds__(256) void loss_kernel(const float* __restrict__ Z,
                                                   const float* __restrict__ wv,
                                                   const int* __restrict__ u,
                                                   const int* __restrict__ v,
                                                   const int* __restrict__ n,
                                                   float* __restrict__ out) {
    int wid = (blockIdx.x * blockDim.x + threadIdx.x) >> 6;
    int lane = threadIdx.x & 63;
    if (wid >= BATCH) return;
    float uu = Z[(size_t)u[wid] * DIM + lane];
    float vv = Z[(size_t)v[wid] * DIM + lane];
    float pos = uu * vv;
    for (int m = 1; m < 64; m <<= 1) pos += __shfl_xor(pos, m);
    float reg = uu * uu + vv * vv;
    float wval = wv[wid];
    float sgn = (wval > 0.f ? 1.f : 0.f) - (wval < 0.f ? 1.f : 0.f);
    float coef = -0.5f * sgn + 1.5f;
    float cp = coef * pos;
    float sb = 0.f;
    for (int k = 0; k < N_NEGS; k++) {
        int nid = n[wid * N_NEGS + k];
        float nn = Z[(size_t)nid * DIM + lane];
        float d = uu * nn;
        for (int m = 1; m < 64; m <<= 1) d += __shfl_xor(d, m);
        reg += nn * nn;
        float x = cp - d;
        float ls = (x >= 0.f) ? -log1pf(expf(-x)) : (x - log1pf(expf(x)));
        sb += ls;
    }
    for (int m = 1; m < 64; m <<= 1) reg += __shfl_xor(reg, m);
    if (lane == 0) atomicAdd(out, -sb + REG_COEF * reg);
}

extern "C" void kernel_launch(void* const* d_in, const int* in_sizes, int n_in,
                              void* d_out, int out_size, void* d_ws, size_t ws_size,
                              hipStream_t stream) {
    const float* E  = (const float*)d_in[0];
    const float* E2 = (const float*)d_in[1];
    const float* W0 = (const float*)d_in[2];
    const float* b0 = (const float*)d_in[3];
    const float* W1 = (const float*)d_in[4];
    const float* b1 = (const float*)d_in[5];
    const float* AW = (const float*)d_in[6];
    const float* ab = (const float*)d_in[7];
    const float* qW = (const float*)d_in[8];
    const float* wv = (const float*)d_in[9];
    const int* ei   = (const int*)d_in[10];
    const int* uu   = (const int*)d_in[11];
    const int* vv   = (const int*)d_in[12];
    const int* nn   = (const int*)d_in[13];
    const int* row = ei;
    const int* col = ei + N_EDGES;

    char* ws = (char*)d_ws;
    size_t p = 0;
    auto align_up = [](size_t x) { return (x + 255) & ~(size_t)255; };
    int* off        = (int*)(ws + p); p = align_up(p + (size_t)(NUM_NODES + 1) * 4);
    float* dinv     = (float*)(ws + p); p = align_up(p + (size_t)NUM_NODES * 4);
    float* sq       = (float*)(ws + p); p = align_up(p + (size_t)NUM_NODES * 4);
    int* hist       = (int*)(ws + p); p = align_up(p + (size_t)HSIZE * 4);
    int* partial    = (int*)(ws + p); p = align_up(p + (size_t)NB2 * 4);
    int* csr_row    = (int*)(ws + p); p = align_up(p + (size_t)N_EDGES * 4);
    char* flags     = (char*)(ws + p); p = align_up(p + (size_t)NUM_NODES);
    int* list       = (int*)(ws + p); p = align_up(p + (size_t)NLIST * 4);
    int* count      = (int*)(ws + p); p = align_up(p + 4);
    __hip_fp8x4_e4m3* xnE4 = (__hip_fp8x4_e4m3*)(ws + p); p = align_up(p + (size_t)NUM_NODES * DIM);
    _Float16* xn1   = (_Float16*)(ws + p); p = align_up(p + (size_t)NUM_NODES * DIM * 2);
    float* x2f      = (float*)(ws + p); p = align_up(p + (size_t)NUM_NODES * DIM * 4);
    float* Z = x2f;                      // alias: fuse reads x2f[nd] then writes Z[nd] same thread
    unsigned* staging = (unsigned*)x2f;  // alias: staging consumed by fill3 before conv2 writes x2f

    hipMemsetAsync(d_out, 0, sizeof(float), stream);
    hipMemsetAsync(flags, 0, (size_t)NUM_NODES, stream);
    hipMemsetAsync(count, 0, 4, stream);

    histo_kernel<<<NT, 256, 0, stream>>>(col, hist);
    scan_partial_kernel<<<NB2, SCAN_B, 0, stream>>>(hist, partial, HSIZE);
    scan_base_kernel<<<1, 64, 0, stream>>>(partial, NB2, 2);
    scan_apply_kernel<<<NB2, SCAN_B, 0, stream>>>(hist, partial, HSIZE);
    partition_kernel<<<NT, 256, 0, stream>>>(row, col, hist, staging);
    fill3_kernel<<<NBK, 512, 0, stream>>>(hist, staging, E, off, dinv, sq, csr_row, xnE4);

    flag_kernel<<<(NLIST + 255) / 256, 256, 0, stream>>>(uu, vv, nn, flags);
    compact_kernel<<<(NUM_NODES + 255) / 256, 256, 0, stream>>>(flags, list, count);

    conv1_kernel<<<NUM_NODES / 4, 256, 0, stream>>>(off, csr_row, dinv, xnE4, xn1);
    conv2_kernel<<<(NLIST + 3) / 4, 256, 0, stream>>>(off, csr_row, dinv, xn1, x2f, list, count);

    fuse_kernel<<<1024, 512, 0, stream>>>(E, E2, W0, b0, W1, b1, AW, ab, qW,
                                          xn1, sq, x2f, Z, list, count);

    loss_kernel<<<BATCH * 64 / 256, 256, 0, stream>>>(Z, wv, uu, vv, nn, (float*)d_out);
}

// Round 7
// 311.579 us; speedup vs baseline: 4.4960x; 1.1894x over previous
//
#include <hip/hip_runtime.h>
#include <hip/hip_fp8.h>
#include <math.h>

#define NUM_NODES 150000
#define DIM 64
#define N_EDGES 3200000
#define BATCH 1024
#define N_NEGS 40
#define REG_COEF 1e-4f

#define BK_BITS 9
#define BK_NODES 512
#define NBK ((NUM_NODES + BK_NODES - 1) >> BK_BITS)      // 293
#define TILE 8192
#define NT ((N_EDGES + TILE - 1) / TILE)                 // 391
#define HSIZE (NBK * NT)                                 // 114563
#define SCAN_B 1024
#define NB2 ((HSIZE + SCAN_B - 1) / SCAN_B)              // 112
#define NLIST (BATCH * (N_NEGS + 2))                     // 43008

// ---------------- pass 1: per-tile bucket histogram ----------------
__global__ __launch_bounds__(256) void histo_kernel(const int* __restrict__ col,
                                                    int* __restrict__ hist) {
    __shared__ int h[NBK];
    int t = threadIdx.x;
    for (int i = t; i < NBK; i += 256) h[i] = 0;
    __syncthreads();
    int e0 = blockIdx.x * TILE;
    int e1 = e0 + TILE; if (e1 > N_EDGES) e1 = N_EDGES;
    for (int i = e0 + t; i < e1; i += 256) atomicAdd(&h[col[i] >> BK_BITS], 1);
    __syncthreads();
    for (int i = t; i < NBK; i += 256) hist[i * NT + blockIdx.x] = h[i];
}

// ---------------- scan (3 kernels) over hist[HSIZE] -> exclusive in-place ----------------
__global__ void scan_partial_kernel(const int* __restrict__ src, int* __restrict__ partial, int n) {
    int t = threadIdx.x;
    int g = blockIdx.x * SCAN_B + t;
    int v = (g < n) ? src[g] : 0;
    for (int m = 1; m < 64; m <<= 1) v += __shfl_xor(v, m);
    __shared__ int ws[16];
    if ((t & 63) == 0) ws[t >> 6] = v;
    __syncthreads();
    if (t < 16) {
        int s = ws[t];
        for (int m = 1; m < 16; m <<= 1) s += __shfl_xor(s, m);
        if (t == 0) partial[blockIdx.x] = s;
    }
}

__global__ void scan_base_kernel(int* __restrict__ partial, int nb, int chunks) {
    int l = threadIdx.x;
    int carry = 0;
    for (int c = 0; c < chunks; c++) {
        int idx = c * 64 + l;
        int v = (idx < nb) ? partial[idx] : 0;
        int inc = v;
        for (int m = 1; m < 64; m <<= 1) {
            int t = __shfl_up(inc, m);
            if (l >= m) inc += t;
        }
        int excl = inc - v + carry;
        if (idx < nb) partial[idx] = excl;
        carry += __shfl(inc, 63);
    }
}

__global__ void scan_apply_kernel(int* __restrict__ data, const int* __restrict__ partial, int n) {
    __shared__ int lds[SCAN_B];
    int t = threadIdx.x;
    int g = blockIdx.x * SCAN_B + t;
    int v = (g < n) ? data[g] : 0;
    int val = v;
    lds[t] = val;
    __syncthreads();
    for (int o = 1; o < SCAN_B; o <<= 1) {
        int add = (t >= o) ? lds[t - o] : 0;
        __syncthreads();
        val += add;
        lds[t] = val;
        __syncthreads();
    }
    if (g < n) data[g] = partial[blockIdx.x] + val - v;  // exclusive
}

// ---------------- pass 2: rank-based partition into bucket-grouped staging ----------------
__global__ __launch_bounds__(256) void partition_kernel(const int* __restrict__ row,
                                                        const int* __restrict__ col,
                                                        const int* __restrict__ hist,
                                                        unsigned* __restrict__ staging) {
    __shared__ int base[NBK];
    __shared__ int cnt[NBK];
    int t = threadIdx.x;
    for (int i = t; i < NBK; i += 256) { base[i] = hist[i * NT + blockIdx.x]; cnt[i] = 0; }
    __syncthreads();
    int e0 = blockIdx.x * TILE;
    int e1 = e0 + TILE; if (e1 > N_EDGES) e1 = N_EDGES;
    for (int i = e0 + t; i < e1; i += 256) {
        int c = col[i];
        int b = c >> BK_BITS;
        int r = atomicAdd(&cnt[b], 1);
        staging[base[b] + r] = ((unsigned)(c & (BK_NODES - 1)) << 18) | (unsigned)row[i];
    }
}

// ------ pass 3: per-bucket offsets + dinv + sq + CSR + pre-scaled fp8 E (x16 scale) ------
__global__ __launch_bounds__(512) void fill3_kernel(const int* __restrict__ hist,
                                                    const unsigned* __restrict__ staging,
                                                    const float* __restrict__ E,
                                                    int* __restrict__ off,
                                                    float* __restrict__ dinv,
                                                    float* __restrict__ sq,
                                                    int* __restrict__ csr_row,
                                                    __hip_fp8x4_e4m3* __restrict__ xnE4) {
    __shared__ int cnt[BK_NODES];
    __shared__ int lds[BK_NODES];
    __shared__ float sdinv[BK_NODES];
    int b = blockIdx.x;
    int t = threadIdx.x;
    int node0 = b << BK_BITS;
    int bstart = hist[b * NT];
    int bend = (b + 1 < NBK) ? hist[(b + 1) * NT] : N_EDGES;
    cnt[t] = 0;
    __syncthreads();
    for (int i = bstart + t; i < bend; i += 512) atomicAdd(&cnt[staging[i] >> 18], 1);
    __syncthreads();
    int v = cnt[t];
    int val = v;
    lds[t] = val;
    __syncthreads();
    for (int o = 1; o < BK_NODES; o <<= 1) {
        int add = (t >= o) ? lds[t - o] : 0;
        __syncthreads();
        val += add;
        lds[t] = val;
        __syncthreads();
    }
    int cursor = bstart + val - v;   // exclusive
    int node = node0 + t;
    float dv = (v > 0) ? rsqrtf((float)v) : 0.f;
    if (node < NUM_NODES) {
        off[node] = cursor;
        dinv[node] = dv;
        sq[node] = sqrtf((float)v);
    }
    sdinv[t] = dv;
    cnt[t] = cursor;
    __syncthreads();
    for (int i = bstart + t; i < bend; i += 512) {
        unsigned s = staging[i];
        int pos = atomicAdd(&cnt[s >> 18], 1);
        csr_row[pos] = (int)(s & 0x3FFFFu);
    }
    // pre-scaled fp8 operand: xnE[node] = e4m3( 16 * dinv[node] * E[node] )
    int nvalid = NUM_NODES - node0; if (nvalid > BK_NODES) nvalid = BK_NODES;
    int groups = nvalid << 4;                         // 16 float4-groups per row
    const float4* E4 = (const float4*)E + ((size_t)node0 << 4);
    __hip_fp8x4_e4m3* out4 = xnE4 + ((size_t)node0 << 4);
    for (int gi = t; gi < groups; gi += 512) {
        float4 e = E4[gi];
        float s = 16.f * sdinv[gi >> 4];
        out4[gi] = __hip_fp8x4_e4m3(make_float4(s * e.x, s * e.y, s * e.z, s * e.w));
    }
    if (b == 0 && t == 0) off[NUM_NODES] = N_EDGES;
}

// ---------------- mark + compact the ~39K nodes the loss actually touches ------------
__global__ void flag_kernel(const int* __restrict__ u, const int* __restrict__ v,
                            const int* __restrict__ n, char* __restrict__ flags) {
    int i = blockIdx.x * blockDim.x + threadIdx.x;
    if (i >= NLIST) return;
    int id;
    if (i < BATCH) id = u[i];
    else if (i < 2 * BATCH) id = v[i - BATCH];
    else id = n[i - 2 * BATCH];
    flags[id] = 1;
}

__global__ void compact_kernel(const char* __restrict__ flags, int* __restrict__ list,
                               int* __restrict__ count) {
    int i = blockIdx.x * blockDim.x + threadIdx.x;
    if (i < NUM_NODES && flags[i]) {
        int pos = atomicAdd(count, 1);
        list[pos] = i;
    }
}

// ---- conv layer 1 (full graph, fp8 operand, one 16-lane group per node):
//      xn1[c] = fp16( dinv[c]^2/16 * sum_in 16*dinv*E[row] )
// lane g of the group owns dims 4g..4g+3; one gather = one 64B line; output row
// stays in the group's registers (no shuffles, no clamping arithmetic).
__global__ __launch_bounds__(256) void conv1_kernel(const int* __restrict__ off,
                                                    const int* __restrict__ csr_row,
                                                    const float* __restrict__ dinv,
                                                    const __hip_fp8x4_e4m3* __restrict__ xq,
                                                    _Float16* __restrict__ yh) {
    int gid = blockIdx.x * blockDim.x + threadIdx.x;
    int grp = gid >> 4;               // node index
    int g = threadIdx.x & 15;         // dim group
    if (grp >= NUM_NODES) return;
    int start = off[grp];
    int end = off[grp + 1];
    float a0 = 0.f, a1 = 0.f, a2 = 0.f, a3 = 0.f;
    int i = start;
    for (; i + 3 < end; i += 4) {
        int r0 = csr_row[i];
        int r1 = csr_row[i + 1];
        int r2 = csr_row[i + 2];
        int r3 = csr_row[i + 3];
        float4 v0 = static_cast<float4>(xq[((size_t)r0 << 4) + g]);
        float4 v1 = static_cast<float4>(xq[((size_t)r1 << 4) + g]);
        float4 v2 = static_cast<float4>(xq[((size_t)r2 << 4) + g]);
        float4 v3 = static_cast<float4>(xq[((size_t)r3 << 4) + g]);
        a0 += v0.x + v1.x + v2.x + v3.x;
        a1 += v0.y + v1.y + v2.y + v3.y;
        a2 += v0.z + v1.z + v2.z + v3.z;
        a3 += v0.w + v1.w + v2.w + v3.w;
    }
    for (; i < end; ++i) {
        int r = csr_row[i];
        float4 v = static_cast<float4>(xq[((size_t)r << 4) + g]);
        a0 += v.x; a1 += v.y; a2 += v.z; a3 += v.w;
    }
    float dv = dinv[grp];
    float s = dv * dv * (1.f / 16.f);
    union { _Float16 h[4]; short4 s4; } u;
    u.h[0] = (_Float16)(s * a0);
    u.h[1] = (_Float16)(s * a1);
    u.h[2] = (_Float16)(s * a2);
    u.h[3] = (_Float16)(s * a3);
    ((short4*)yh)[((size_t)grp << 4) + g] = u.s4;
}

// ---- conv layer 2 (listed nodes, fp16 operand, one 16-lane group per node):
//      x2[c] = dinv[c] * sum_in xn1[row]
__global__ __launch_bounds__(256) void conv2_kernel(const int* __restrict__ off,
                                                    const int* __restrict__ csr_row,
                                                    const float* __restrict__ dinv,
                                                    const _Float16* __restrict__ xh,
                                                    float* __restrict__ x2,
                                                    const int* __restrict__ list,
                                                    const int* __restrict__ count) {
    int gid = blockIdx.x * blockDim.x + threadIdx.x;
    int li = gid >> 4;
    int g = threadIdx.x & 15;
    if (li >= *count) return;
    int nd = list[li];
    int start = off[nd];
    int end = off[nd + 1];
    const short4* xh4 = (const short4*)xh;
    float a0 = 0.f, a1 = 0.f, a2 = 0.f, a3 = 0.f;
    int i = start;
    for (; i + 3 < end; i += 4) {
        int r0 = csr_row[i];
        int r1 = csr_row[i + 1];
        int r2 = csr_row[i + 2];
        int r3 = csr_row[i + 3];
        union { short4 s4; _Float16 h[4]; } u0, u1, u2, u3;
        u0.s4 = xh4[((size_t)r0 << 4) + g];
        u1.s4 = xh4[((size_t)r1 << 4) + g];
        u2.s4 = xh4[((size_t)r2 << 4) + g];
        u3.s4 = xh4[((size_t)r3 << 4) + g];
        a0 += (float)u0.h[0] + (float)u1.h[0] + (float)u2.h[0] + (float)u3.h[0];
        a1 += (float)u0.h[1] + (float)u1.h[1] + (float)u2.h[1] + (float)u3.h[1];
        a2 += (float)u0.h[2] + (float)u1.h[2] + (float)u2.h[2] + (float)u3.h[2];
        a3 += (float)u0.h[3] + (float)u1.h[3] + (float)u2.h[3] + (float)u3.h[3];
    }
    for (; i < end; ++i) {
        int r = csr_row[i];
        union { short4 s4; _Float16 h[4]; } u;
        u.s4 = xh4[((size_t)r << 4) + g];
        a0 += (float)u.h[0]; a1 += (float)u.h[1];
        a2 += (float)u.h[2]; a3 += (float)u.h[3];
    }
    float dv = dinv[nd];
    ((float4*)x2)[((size_t)nd << 4) + g] = make_float4(dv * a0, dv * a1, dv * a2, dv * a3);
}

// ---------------- fused node-wise over listed nodes; wave-independent ----------------
__global__ __launch_bounds__(512) void fuse_kernel(
    const float* __restrict__ E, const float* __restrict__ E2,
    const float* __restrict__ W0, const float* __restrict__ b0,
    const float* __restrict__ W1, const float* __restrict__ b1,
    const float* __restrict__ AW, const float* __restrict__ ab,
    const float* __restrict__ qW,
    const _Float16* __restrict__ xn1, const float* __restrict__ sq,
    const float* x2, float* Z,
    const int* __restrict__ list, const int* __restrict__ count) {
    __shared__ __align__(16) float W0q[4096];
    __shared__ __align__(16) float W1q[4096];
    __shared__ __align__(16) float AWq[4096];
    __shared__ float bb0[64], bb1[64], bab[64], qb[64];
    __shared__ __align__(16) float xbuf[8][64];
    __shared__ __align__(16) float hbuf[8][64];
    __shared__ __align__(16) float zpb[8][64];
    __shared__ __align__(16) float znb[8][64];

    int t = threadIdx.x;
    for (int idx = t; idx < 4096; idx += 512) {
        int j = idx >> 6, k = idx & 63;
        int dst = (k >> 2) * 256 + j * 4 + (k & 3);
        W0q[dst] = W0[idx];
        W1q[dst] = W1[idx];
        AWq[dst] = AW[idx];
    }
    if (t < 64) { bb0[t] = b0[t]; bb1[t] = b1[t]; bab[t] = ab[t]; qb[t] = qW[t]; }
    __syncthreads();   // weights staged once; the node loop below is wave-local

    const int lane = t & 63, w = t >> 6;
    const int cnt = *count;
    for (int li = blockIdx.x * 8 + w; li < cnt; li += gridDim.x * 8) {
        int nd = list[li];
        size_t base = ((size_t)nd << 6) + lane;
        float x1v = sq[nd] * (float)xn1[base];
        float zp = (E[base] + x1v + x2[base]) * (1.f / 3.f);
        float e2v = E2[base];
        zpb[w][lane] = zp;
        xbuf[w][lane] = e2v;
        __builtin_amdgcn_wave_barrier();

        float s = bb0[lane];
#pragma unroll
        for (int k4 = 0; k4 < 16; k4++) {
            float4 wq = *(const float4*)&W0q[k4 * 256 + lane * 4];
            float4 xq = *(const float4*)&xbuf[w][k4 * 4];
            s += wq.x * xq.x + wq.y * xq.y + wq.z * xq.z + wq.w * xq.w;
        }
        float h = fmaxf(s, 0.f);
        hbuf[w][lane] = h;
        __builtin_amdgcn_wave_barrier();

        s = bb1[lane];
#pragma unroll
        for (int k4 = 0; k4 < 16; k4++) {
            float4 wq = *(const float4*)&W1q[k4 * 256 + lane * 4];
            float4 xq = *(const float4*)&hbuf[w][k4 * 4];
            s += wq.x * xq.x + wq.y * xq.y + wq.z * xq.z + wq.w * xq.w;
        }
        float zn = fmaxf(s, 0.f);
        znb[w][lane] = zn;
        __builtin_amdgcn_wave_barrier();

        float sp = bab[lane], sn = bab[lane];
#pragma unroll
        for (int k4 = 0; k4 < 16; k4++) {
            float4 wq = *(const float4*)&AWq[k4 * 256 + lane * 4];
            float4 zq = *(const float4*)&zpb[w][k4 * 4];
            float4 nq = *(const float4*)&znb[w][k4 * 4];
            sp += wq.x * zq.x + wq.y * zq.y + wq.z * zq.z + wq.w * zq.w;
            sn += wq.x * nq.x + wq.y * nq.y + wq.z * nq.z + wq.w * nq.w;
        }
        float tp = tanhf(sp) * qb[lane];
        float tn = tanhf(sn) * qb[lane];
        for (int m = 1; m < 64; m <<= 1) {
            tp += __shfl_xor(tp, m);
            tn += __shfl_xor(tn, m);
        }
        float mx = fmaxf(tp, tn);
        float ep = expf(tp - mx), en = expf(tn - mx);
        float inv = 1.f / (ep + en);
        Z[base] = (ep * zp + en * zn) * inv;
        __builtin_amdgcn_wave_barrier();
    }
}

// ---------------- loss ----------------
__global__ __launch_bounds__(256) void loss_kernel(const float* __restrict__ Z,
                                                   const float* __restrict__ wv,
                                                   const int* __restrict__ u,
                                                   const int* __restrict__ v,
                                                   const int* __restrict__ n,
                                                   float* __restrict__ out) {
    int wid = (blockIdx.x * blockDim.x + threadIdx.x) >> 6;
    int lane = threadIdx.x & 63;
    if (wid >= BATCH) return;
    float uu = Z[(size_t)u[wid] * DIM + lane];
    float vv = Z[(size_t)v[wid] * DIM + lane];
    float pos = uu * vv;
    for (int m = 1; m < 64; m <<= 1) pos += __shfl_xor(pos, m);
    float reg = uu * uu + vv * vv;
    float wval = wv[wid];
    float sgn = (wval > 0.f ? 1.f : 0.f) - (wval < 0.f ? 1.f : 0.f);
    float coef = -0.5f * sgn + 1.5f;
    float cp = coef * pos;
    float sb = 0.f;
    for (int k = 0; k < N_NEGS; k++) {
        int nid = n[wid * N_NEGS + k];
        float nn = Z[(size_t)nid * DIM + lane];
        float d = uu * nn;
        for (int m = 1; m < 64; m <<= 1) d += __shfl_xor(d, m);
        reg += nn * nn;
        float x = cp - d;
        float ls = (x >= 0.f) ? -log1pf(expf(-x)) : (x - log1pf(expf(x)));
        sb += ls;
    }
    for (int m = 1; m < 64; m <<= 1) reg += __shfl_xor(reg, m);
    if (lane == 0) atomicAdd(out, -sb + REG_COEF * reg);
}

extern "C" void kernel_launch(void* const* d_in, const int* in_sizes, int n_in,
                              void* d_out, int out_size, void* d_ws, size_t ws_size,
                              hipStream_t stream) {
    const float* E  = (const float*)d_in[0];
    const float* E2 = (const float*)d_in[1];
    const float* W0 = (const float*)d_in[2];
    const float* b0 = (const float*)d_in[3];
    const float* W1 = (const float*)d_in[4];
    const float* b1 = (const float*)d_in[5];
    const float* AW = (const float*)d_in[6];
    const float* ab = (const float*)d_in[7];
    const float* qW = (const float*)d_in[8];
    const float* wv = (const float*)d_in[9];
    const int* ei   = (const int*)d_in[10];
    const int* uu   = (const int*)d_in[11];
    const int* vv   = (const int*)d_in[12];
    const int* nn   = (const int*)d_in[13];
    const int* row = ei;
    const int* col = ei + N_EDGES;

    char* ws = (char*)d_ws;
    size_t p = 0;
    auto align_up = [](size_t x) { return (x + 255) & ~(size_t)255; };
    int* off        = (int*)(ws + p); p = align_up(p + (size_t)(NUM_NODES + 1) * 4);
    float* dinv     = (float*)(ws + p); p = align_up(p + (size_t)NUM_NODES * 4);
    float* sq       = (float*)(ws + p); p = align_up(p + (size_t)NUM_NODES * 4);
    int* hist       = (int*)(ws + p); p = align_up(p + (size_t)HSIZE * 4);
    int* partial    = (int*)(ws + p); p = align_up(p + (size_t)NB2 * 4);
    int* csr_row    = (int*)(ws + p); p = align_up(p + (size_t)N_EDGES * 4);
    char* flags     = (char*)(ws + p); p = align_up(p + (size_t)NUM_NODES);
    int* list       = (int*)(ws + p); p = align_up(p + (size_t)NLIST * 4);
    int* count      = (int*)(ws + p); p = align_up(p + 4);
    __hip_fp8x4_e4m3* xnE4 = (__hip_fp8x4_e4m3*)(ws + p); p = align_up(p + (size_t)NUM_NODES * DIM);
    _Float16* xn1   = (_Float16*)(ws + p); p = align_up(p + (size_t)NUM_NODES * DIM * 2);
    float* x2f      = (float*)(ws + p); p = align_up(p + (size_t)NUM_NODES * DIM * 4);
    float* Z = x2f;                      // alias: fuse reads x2f[nd] then writes Z[nd] same thread
    unsigned* staging = (unsigned*)x2f;  // alias: staging consumed by fill3 before conv2 writes x2f

    hipMemsetAsync(d_out, 0, sizeof(float), stream);
    hipMemsetAsync(flags, 0, (size_t)NUM_NODES, stream);
    hipMemsetAsync(count, 0, 4, stream);

    histo_kernel<<<NT, 256, 0, stream>>>(col, hist);
    scan_partial_kernel<<<NB2, SCAN_B, 0, stream>>>(hist, partial, HSIZE);
    scan_base_kernel<<<1, 64, 0, stream>>>(partial, NB2, 2);
    scan_apply_kernel<<<NB2, SCAN_B, 0, stream>>>(hist, partial, HSIZE);
    partition_kernel<<<NT, 256, 0, stream>>>(row, col, hist, staging);
    fill3_kernel<<<NBK, 512, 0, stream>>>(hist, staging, E, off, dinv, sq, csr_row, xnE4);

    flag_kernel<<<(NLIST + 255) / 256, 256, 0, stream>>>(uu, vv, nn, flags);
    compact_kernel<<<(NUM_NODES + 255) / 256, 256, 0, stream>>>(flags, list, count);

    conv1_kernel<<<(NUM_NODES * 16 + 255) / 256, 256, 0, stream>>>(off, csr_row, dinv, xnE4, xn1);
    conv2_kernel<<<(NLIST * 16 + 255) / 256, 256, 0, stream>>>(off, csr_row, dinv, xn1, x2f, list, count);

    fuse_kernel<<<1024, 512, 0, stream>>>(E, E2, W0, b0, W1, b1, AW, ab, qW,
                                          xn1, sq, x2f, Z, list, count);

    loss_kernel<<<BATCH * 64 / 256, 256, 0, stream>>>(Z, wv, uu, vv, nn, (float*)d_out);
}